// Round 4
// baseline (2008.716 us; speedup 1.0000x reference)
//
#include <hip/hip_runtime.h>
#include <stdint.h>

// CfC RNN: B=256, T=1024, I=64, U=256, O=64, BB=128. All I/O float32.
//
// Round 4: 16-wave (1024-thread) MFMA kernel, 16 WGs (16 rows each).
// Rationale: r1/r3 ran 8 waves -> 2 waves/SIMD; per-step time ~3920 cyc vs
// ~1600 cyc of issue => stall-bound. This version runs 4 waves/SIMD and
// splits work finer:
//   bb:  Z[16x320] @ W_bb[320x128]; 8 n-tiles x 2 K-halves = 16 waves,
//        5 MFMAs each; K-halves summed via LDS partial buffer (s_red).
//   ff:  G[16x128] @ [Wff1|Wff2|Wta+Wtb][128x768]; wave w owns units
//        [16w,16w+16): 12 MFMAs; epilogue = 4 h/thread (was 8).
//   x-staging owned by waves 8-15, written mid-ff (large vmcnt slack).
//   h-epi refactored to ONE rcp: h = 1 + 2R[(E2-E1) - (E2+1)(E3+1)],
//        R = rcp((E1+1)(E2+1)(E3+1))  -> 4 trans/h instead of 6.
//   Barriers: lgkm-only (3/step) -- stores are issued right before the
//        step-end barrier, a vmcnt(0) drain there would serialize them.
// LDS XOR swizzle (bijective, bit2^=bit6 of word index) kept from r3.
#define B_ 256
#define T_ 1024
#define I_ 64
#define U_ 256
#define O_ 64
#define BB_ 128

typedef unsigned int u32;
typedef unsigned short u16;
typedef _Float16 half2_t __attribute__((ext_vector_type(2)));
typedef _Float16 f16x8 __attribute__((ext_vector_type(8)));
typedef float f32x4 __attribute__((ext_vector_type(4)));

#if defined(__has_builtin)
#if __has_builtin(__builtin_amdgcn_fdot2)
#define USE_DOT2 1
#else
#define USE_DOT2 0
#endif
#else
#define USE_DOT2 0
#endif

static __device__ __forceinline__ u32 packpair(float a, float b) {
  half2_t h; h.x = (_Float16)a; h.y = (_Float16)b;
  return __builtin_bit_cast(u32, h);
}
static __device__ __forceinline__ float unpack_lo(u32 u) {
  half2_t h = __builtin_bit_cast(half2_t, u); return (float)h.x;
}
static __device__ __forceinline__ float unpack_hi(u32 u) {
  half2_t h = __builtin_bit_cast(half2_t, u); return (float)h.y;
}
static __device__ __forceinline__ float dot2acc(u32 w, u32 z, float acc) {
#if USE_DOT2
  return __builtin_amdgcn_fdot2(__builtin_bit_cast(half2_t, w),
                                __builtin_bit_cast(half2_t, z), acc, false);
#else
  half2_t hw = __builtin_bit_cast(half2_t, w);
  half2_t hz = __builtin_bit_cast(half2_t, z);
  acc += (float)hw.x * (float)hz.x;
  acc += (float)hw.y * (float)hz.y;
  return acc;
#endif
}

// DPP cross-lane moves (VALU pipe; no LDS). Palindromic controls only.
template <int CTRL>
static __device__ __forceinline__ float dpp_mov_f(float v) {
  return __builtin_bit_cast(float, __builtin_amdgcn_update_dpp(
      0, __builtin_bit_cast(int, v), CTRL, 0xF, 0xF, true));
}
#define DPP_XOR1 0xB1
#define DPP_XOR2 0x4E
#define DPP_HMIR 0x141
#define DPP_MIRR 0x140

static __device__ __forceinline__ float fast_tanh(float x) {
  return 1.0f - 2.0f / (1.0f + __expf(2.0f * x));
}
static __device__ __forceinline__ float fast_sigmoid(float x) {
  return 1.0f / (1.0f + __expf(-x));
}

static __device__ __forceinline__ float rcpf(float x) {
#if defined(__has_builtin) && __has_builtin(__builtin_amdgcn_rcpf)
  return __builtin_amdgcn_rcpf(x);
#else
  return 1.0f / x;
#endif
}
static __device__ __forceinline__ float exp2fast(float x) {
#if defined(__has_builtin) && __has_builtin(__builtin_amdgcn_exp2f)
  return __builtin_amdgcn_exp2f(x);
#else
  return exp2f(x);
#endif
}

static __device__ __forceinline__ f32x4 mfma16(uint4 a, uint4 b, f32x4 c) {
  return __builtin_amdgcn_mfma_f32_16x16x32_f16(
      __builtin_bit_cast(f16x8, a), __builtin_bit_cast(f16x8, b), c, 0, 0, 0);
}

// LDS-only barrier: do NOT drain vmcnt (global loads/stores keep flying).
static __device__ __forceinline__ void wg_barrier() {
  asm volatile("s_waitcnt lgkmcnt(0)\n\ts_barrier" ::: "memory");
}

// Bijective self-inverse LDS word-index swizzle: flip bit2 with bit6.
static __device__ __forceinline__ int swzw(int w) {
  return w ^ ((w >> 4) & 4);
}

#define LOG2E 1.44269504f

// ============================ MFMA main kernel ============================
__global__ __launch_bounds__(1024, 4)
void cfc_mfma(const float* __restrict__ x,
              const float* __restrict__ W_bb, const float* __restrict__ b_bb,
              const float* __restrict__ W_ff1, const float* __restrict__ b_ff1,
              const float* __restrict__ W_ff2, const float* __restrict__ b_ff2,
              const float* __restrict__ W_ta,  const float* __restrict__ b_ta,
              const float* __restrict__ W_tb,  const float* __restrict__ b_tb,
              float* __restrict__ out, u32* __restrict__ Hbuf)
{
  // z A-frags: words [10 chunks][64 lanes][4 u32], XOR-swizzled.
  //   chunks 0..1 = x_t (k=0..63), chunks 2..9 = h (k=64..319).
  __shared__ __align__(16) u32 s_z[2560];
  // g A-frags: [4 chunks][64 lanes][4 u32].
  __shared__ __align__(16) u32 s_g[1024];
  // bb K-split partials: [8 tiles][64 lanes][4 f32].
  __shared__ __align__(16) float s_red[2048];

  const int tid = threadIdx.x;
  const int l   = tid & 63;        // lane
  const int w   = tid >> 6;        // wave 0..15
  const int wt  = w & 7;           // bb n-tile
  const int kh  = w >> 3;          // bb K-half
  const int c16 = l & 15;
  const int q4  = l >> 4;
  const int odd = l & 1;
  const int row0 = blockIdx.x * 16;
  const int lr  = l ^ ((l >> 4) & 1);   // swizzled uint4-read lane

  // ---- bb weights: this wave's K-half (5 chunks), n-tile wt ----
  uint4 wbb[5];
  {
    const int colb = wt * 16 + c16;
#pragma unroll
    for (int c = 0; c < 5; ++c) {
      const int kc = kh * 5 + c;
      u32 qv[4];
#pragma unroll
      for (int q = 0; q < 4; ++q) {
        const int k0 = kc * 32 + q4 * 8 + 2 * q;
        qv[q] = packpair(W_bb[(size_t)k0 * BB_ + colb],
                         W_bb[(size_t)(k0 + 1) * BB_ + colb]);
      }
      wbb[c] = make_uint4(qv[0], qv[1], qv[2], qv[3]);
    }
  }
  // ---- ff weights: wave w owns units [16w, 16w+16); 3 mats x 4 chunks ----
  uint4 wff0[4], wff1[4], wff2[4];
  const int uu = w * 16 + c16;
#pragma unroll
  for (int c = 0; c < 4; ++c) {
    u32 qa[4], qb[4], qc[4];
#pragma unroll
    for (int q = 0; q < 4; ++q) {
      const int k0 = c * 32 + q4 * 8 + 2 * q;
      const size_t i0 = (size_t)k0 * U_ + uu, i1 = i0 + U_;
      qa[q] = packpair(W_ff1[i0], W_ff1[i1]);
      qb[q] = packpair(W_ff2[i0], W_ff2[i1]);
      qc[q] = packpair(W_ta[i0] + W_tb[i0], W_ta[i1] + W_tb[i1]);
    }
    wff0[c] = make_uint4(qa[0], qa[1], qa[2], qa[3]);
    wff1[c] = make_uint4(qb[0], qb[1], qb[2], qb[3]);
    wff2[c] = make_uint4(qc[0], qc[1], qc[2], qc[3]);
  }

  // ---- biases, pre-scaled for exp2 forms ----
  const float bgs = b_bb[wt * 16 + c16] * (1.332f * LOG2E);
  const float b1s = b_ff1[uu] * (2.0f * LOG2E);
  const float b2s = b_ff2[uu] * (2.0f * LOG2E);
  const float btn = -(b_ta[uu] + b_tb[uu]) * LOG2E;

  // ---- x staging (waves 8-15): thread i=tid&511: row mx, pair px ----
  const int ix = tid & 511;
  const int mx = ix >> 5, px = ix & 31;
  const float* xptr = x + (size_t)(row0 + mx) * T_ * I_ + 2 * px;
  const int zxs = swzw((px >> 4) * 256 + 64 * ((px >> 2) & 3) + 4 * mx + (px & 3));

  // ---- g staging (waves 0-7): pair pg, rows m0/m0+1 ----
  const int m0 = 4 * q4 + 2 * odd;
  const int pg = wt * 8 + (c16 >> 1);
  const int gW = (pg >> 4) * 256 + 64 * ((pg >> 2) & 3) + (pg & 3) + 4 * m0;
  const int gws0 = swzw(gW), gws1 = swzw(gW + 4);

  // ---- h staging (all waves): pair pu, z-pair pz = 32+pu ----
  const int pu = w * 8 + (c16 >> 1);
  const int pz = 32 + pu;
  const int zW = (pz >> 4) * 256 + 64 * ((pz >> 2) & 3) + (pz & 3) + 4 * m0;
  const int zws0 = swzw(zW), zws1 = swzw(zW + 4);
  const u32 hoff0 = (u32)(row0 + m0) * T_ * 128 + pu;
  const u32 hoff1 = hoff0 + (u32)T_ * 128;

  // ---- bb partial exchange slot (same for the (wt,kh) pair) ----
  const int redw = (wt * 64 + l) * 4;

  // ---- prologue: zero s_z, stage x_0 ----
  {
    uint4* z4w = reinterpret_cast<uint4*>(s_z);
    if (tid < 640) z4w[tid] = make_uint4(0u, 0u, 0u, 0u);
  }
  __syncthreads();
  if (w >= 8) {
    float2 x0 = *(const float2*)xptr;
    s_z[zxs] = packpair(x0.x, x0.y);
  }
  __syncthreads();

  const uint4* z4 = (const uint4*)s_z;
  const uint4* g4 = (const uint4*)s_g;

  for (int t = 0; t < T_; ++t) {
    // x(t+1) prefetch by waves 8-15 (consumed mid-ff below)
    float2 xv;
    const bool ldx = (w >= 8) && (t + 1 < T_);
    if (ldx) xv = *(const float2*)(xptr + (size_t)(t + 1) * I_);

    // ============ bb: partial G = Z[:, kh-half] @ W_bb ============
    f32x4 aA = {0.f, 0.f, 0.f, 0.f}, aB = {0.f, 0.f, 0.f, 0.f};
    {
      const int cb = kh * 5;
      aA = mfma16(z4[(cb + 0) * 64 + lr], wbb[0], aA);
      aB = mfma16(z4[(cb + 1) * 64 + lr], wbb[1], aB);
      aA = mfma16(z4[(cb + 2) * 64 + lr], wbb[2], aA);
      aB = mfma16(z4[(cb + 3) * 64 + lr], wbb[3], aB);
      aA = mfma16(z4[(cb + 4) * 64 + lr], wbb[4], aA);
    }
    const f32x4 ab = aA + aB;
    if (kh) *(f32x4*)(s_red + redw) = ab;
    wg_barrier();  // bar1: partials visible

    // ============ bb reduce + g epilogue (waves 0-7) ============
    if (!kh) {
      const f32x4 pr = *(const f32x4*)(s_red + redw);
      u32 gq[4];
#pragma unroll
      for (int r = 0; r < 4; ++r) {
        const float full = ab[r] + pr[r];
        const float a  = __builtin_fmaf(full, 1.332f * LOG2E, bgs);
        const float rr = rcpf(exp2fast(a) + 1.0f);
        const float g  = __builtin_fmaf(rr, -3.4318f, 1.7159f);
        const float gp = dpp_mov_f<DPP_XOR1>(g);
        gq[r] = odd ? packpair(gp, g) : packpair(g, gp);
      }
      s_g[gws0] = odd ? gq[2] : gq[0];
      s_g[gws1] = odd ? gq[3] : gq[1];
    }
    wg_barrier();  // bar2: g visible

    // ============ ff: [E1|E2|E3] = G @ Wcat ============
    f32x4 af0 = {0.f, 0.f, 0.f, 0.f};
    f32x4 af1 = {0.f, 0.f, 0.f, 0.f};
    f32x4 af2 = {0.f, 0.f, 0.f, 0.f};
#pragma unroll
    for (int c = 0; c < 4; ++c) {
      const uint4 ga = g4[c * 64 + lr];
      af0 = mfma16(ga, wff0[c], af0);
      af1 = mfma16(ga, wff1[c], af1);
      af2 = mfma16(ga, wff2[c], af2);
    }
    // stage x(t+1) here: vmcnt wait covered by bb+epi+ff (~1000 cyc slack)
    if (ldx) s_z[zxs] = packpair(xv.x, xv.y);

    // ============ combine -> h (one-rcp form); stage; Hbuf ============
    u32 hq[4];
#pragma unroll
    for (int r = 0; r < 4; ++r) {
      const float E1 = exp2fast(__builtin_fmaf(af0[r], 2.0f * LOG2E, b1s));
      const float E2 = exp2fast(__builtin_fmaf(af1[r], 2.0f * LOG2E, b2s));
      const float E3 = exp2fast(__builtin_fmaf(af2[r], -LOG2E, btn));
      const float p2 = E2 + 1.0f, p3 = E3 + 1.0f;
      const float qq = p2 * p3;
      const float D  = __builtin_fmaf(E1, qq, qq);   // (E1+1)(E2+1)(E3+1)
      const float R  = rcpf(D);
      const float u2 = (E2 - E1) - qq;
      const float h  = __builtin_fmaf(R + R, u2, 1.0f);
      const float hp = dpp_mov_f<DPP_XOR1>(h);
      hq[r] = odd ? packpair(hp, h) : packpair(h, hp);
    }
    const u32 s0 = odd ? hq[2] : hq[0];
    const u32 s1 = odd ? hq[3] : hq[1];
    s_z[zws0] = s0;
    s_z[zws1] = s1;
    Hbuf[hoff0 + (u32)t * 128] = s0;
    Hbuf[hoff1 + (u32)t * 128] = s1;
    wg_barrier();  // bar3: z(t+1) ready
  }

  // ---- h_last tail: unpack h region of s_z -> out + B*T*O as float2 ----
  if (tid < 512) {
    const uint4 hv = z4[128 + (tid ^ ((tid >> 4) & 1))];
    float2* tail = (float2*)(out + (size_t)B_ * T_ * O_);
#pragma unroll
    for (int i = 0; i < 4; ++i) {
      const int vh   = tid * 4 + i;          // logical word in h region
      const int ch   = vh >> 8;
      const int lane = (vh >> 2) & 63;
      const int slot = vh & 3;
      const int m    = lane & 15;
      const int bq   = lane >> 4;
      const int pp   = ch * 16 + bq * 4 + slot;
      const u32 hp   = (i == 0) ? hv.x : (i == 1) ? hv.y : (i == 2) ? hv.z : hv.w;
      float2 hf; hf.x = unpack_lo(hp); hf.y = unpack_hi(hp);
      tail[(size_t)(row0 + m) * 128 + pp] = hf;
    }
  }
}

// ================= fallback (no workspace): dot2 kernel ==========
template <bool DEFER>
__global__ __launch_bounds__(1024)
void cfc_kernel(const float* __restrict__ x,
                const float* __restrict__ W_bb, const float* __restrict__ b_bb,
                const float* __restrict__ W_ff1, const float* __restrict__ b_ff1,
                const float* __restrict__ W_ff2, const float* __restrict__ b_ff2,
                const float* __restrict__ W_ta,  const float* __restrict__ b_ta,
                const float* __restrict__ W_tb,  const float* __restrict__ b_tb,
                const float* __restrict__ W_fc,  const float* __restrict__ b_fc,
                float* __restrict__ out, u32* __restrict__ Hbuf)
{
  __shared__ __align__(16) u32 s_z2[160];
  __shared__ __align__(16) u32 s_g2[64];
  u16* s_gh = (u16*)s_g2;

  const int tid = threadIdx.x;
  const int r   = blockIdx.x;

  const int ca  = tid >> 3;
  const int kga = tid & 7;
  const int jb = tid >> 2;
  const int kq = tid & 3;
  const int ro = tid >> 4;
  const int rk = tid & 15;

  u32 wbb[20];
#pragma unroll
  for (int j = 0; j < 5; ++j)
#pragma unroll
    for (int q = 0; q < 4; ++q) {
      int p = 4 * (kga + 8 * j) + q;
      wbb[4 * j + q] = packpair(W_bb[(2 * p) * BB_ + ca],
                                W_bb[(2 * p + 1) * BB_ + ca]);
    }
  u32 wf1[16], wf2[16], wta[16], wtb[16];
#pragma unroll
  for (int j = 0; j < 4; ++j)
#pragma unroll
    for (int q = 0; q < 4; ++q) {
      int p = 4 * (kq + 4 * j) + q;
      int k0 = 2 * p, k1 = 2 * p + 1;
      wf1[4 * j + q] = packpair(W_ff1[k0 * U_ + jb], W_ff1[k1 * U_ + jb]);
      wf2[4 * j + q] = packpair(W_ff2[k0 * U_ + jb], W_ff2[k1 * U_ + jb]);
      wta[4 * j + q] = packpair(W_ta [k0 * U_ + jb], W_ta [k1 * U_ + jb]);
      wtb[4 * j + q] = packpair(W_tb [k0 * U_ + jb], W_tb [k1 * U_ + jb]);
    }
  u32 wfc[8];
  float bfo = 0.f;
  if (!DEFER) {
#pragma unroll
    for (int j = 0; j < 2; ++j)
#pragma unroll
      for (int q = 0; q < 4; ++q) {
        int p = 4 * (rk + 16 * j) + q;
        wfc[4 * j + q] = packpair(W_fc[(2 * p) * O_ + ro],
                                  W_fc[(2 * p + 1) * O_ + ro]);
      }
    bfo = b_fc[ro];
  }
  const float bbbc = b_bb[ca];
  const float b1 = b_ff1[jb], b2 = b_ff2[jb];
  const float bta = b_ta[jb], btb = b_tb[jb];

  const float* xrow = x + (size_t)r * T_ * I_;
  const size_t out_row = (size_t)r * T_ * O_;
  u32* __restrict__ hrow = DEFER ? (Hbuf + (size_t)r * T_ * (U_ / 2)) : nullptr;

  if (tid < 160) s_z2[tid] = 0u;
  __syncthreads();
  if (tid < 32) {
    float2 xv = ((const float2*)xrow)[tid];
    s_z2[tid] = packpair(xv.x, xv.y);
  }
  __syncthreads();

  for (int t = 0; t < T_; ++t) {
    float2 xv;
    const bool ldx = (tid < 32) && (t + 1 < T_);
    if (ldx) xv = ((const float2*)(xrow + (size_t)(t + 1) * I_))[tid];

    float bacc = 0.f;
#pragma unroll
    for (int j = 0; j < 5; ++j) {
      uint4 zz = *reinterpret_cast<const uint4*>(s_z2 + 4 * (kga + 8 * j));
      bacc = dot2acc(wbb[4 * j + 0], zz.x, bacc);
      bacc = dot2acc(wbb[4 * j + 1], zz.y, bacc);
      bacc = dot2acc(wbb[4 * j + 2], zz.z, bacc);
      bacc = dot2acc(wbb[4 * j + 3], zz.w, bacc);
    }
    bacc += dpp_mov_f<DPP_XOR1>(bacc);
    bacc += dpp_mov_f<DPP_XOR2>(bacc);
    bacc += dpp_mov_f<DPP_HMIR>(bacc);
    float g = 1.7159f * fast_tanh(0.666f * (bacc + bbbc));

    float racc = 0.f;
    if (!DEFER) {
#pragma unroll
      for (int j = 0; j < 2; ++j) {
        uint4 hh = *reinterpret_cast<const uint4*>(s_z2 + 32 + 4 * (rk + 16 * j));
        racc = dot2acc(wfc[4 * j + 0], hh.x, racc);
        racc = dot2acc(wfc[4 * j + 1], hh.y, racc);
        racc = dot2acc(wfc[4 * j + 2], hh.z, racc);
        racc = dot2acc(wfc[4 * j + 3], hh.w, racc);
      }
      racc += dpp_mov_f<DPP_XOR1>(racc);
      racc += dpp_mov_f<DPP_XOR2>(racc);
      racc += dpp_mov_f<DPP_HMIR>(racc);
      racc += dpp_mov_f<DPP_MIRR>(racc);
    }
    if ((tid & 7) == 0)
      s_gh[ca] = __builtin_bit_cast(u16, (_Float16)g);
    if (!DEFER && t > 0 && rk == 0)
      out[out_row + (size_t)(t - 1) * O_ + ro] = racc + bfo;
    __syncthreads();

    float a1 = 0.f, a2 = 0.f, a3 = 0.f, a4 = 0.f;
#pragma unroll
    for (int j = 0; j < 4; ++j) {
      uint4 gg = *reinterpret_cast<const uint4*>(s_g2 + 4 * (kq + 4 * j));
      a1 = dot2acc(wf1[4 * j + 0], gg.x, a1);
      a1 = dot2acc(wf1[4 * j + 1], gg.y, a1);
      a1 = dot2acc(wf1[4 * j + 2], gg.z, a1);
      a1 = dot2acc(wf1[4 * j + 3], gg.w, a1);
      a2 = dot2acc(wf2[4 * j + 0], gg.x, a2);
      a2 = dot2acc(wf2[4 * j + 1], gg.y, a2);
      a2 = dot2acc(wf2[4 * j + 2], gg.z, a2);
      a2 = dot2acc(wf2[4 * j + 3], gg.w, a2);
      a3 = dot2acc(wta[4 * j + 0], gg.x, a3);
      a3 = dot2acc(wta[4 * j + 1], gg.y, a3);
      a3 = dot2acc(wta[4 * j + 2], gg.z, a3);
      a3 = dot2acc(wta[4 * j + 3], gg.w, a3);
      a4 = dot2acc(wtb[4 * j + 0], gg.x, a4);
      a4 = dot2acc(wtb[4 * j + 1], gg.y, a4);
      a4 = dot2acc(wtb[4 * j + 2], gg.z, a4);
      a4 = dot2acc(wtb[4 * j + 3], gg.w, a4);
    }
    a1 += dpp_mov_f<DPP_XOR1>(a1); a1 += dpp_mov_f<DPP_XOR2>(a1);
    a2 += dpp_mov_f<DPP_XOR1>(a2); a2 += dpp_mov_f<DPP_XOR2>(a2);
    a3 += dpp_mov_f<DPP_XOR1>(a3); a3 += dpp_mov_f<DPP_XOR2>(a3);
    a4 += dpp_mov_f<DPP_XOR1>(a4); a4 += dpp_mov_f<DPP_XOR2>(a4);
    float f1 = fast_tanh(a1 + b1);
    float f2 = fast_tanh(a2 + b2);
    float ti = fast_sigmoid(a3 + bta + a4 + btb);
    float h  = f1 + ti * (f2 - f1);
    float hq = dpp_mov_f<DPP_HMIR>(h);

    if ((tid & 7) == 0) {
      u32 pr = packpair(h, hq);
      int m = tid >> 3;
      s_z2[32 + m] = pr;
      if (DEFER) hrow[(size_t)t * (U_ / 2) + m] = pr;
    }
    if (ldx) s_z2[tid] = packpair(xv.x, xv.y);
    __syncthreads();
  }

  if (!DEFER) {
    float racc = 0.f;
#pragma unroll
    for (int j = 0; j < 2; ++j) {
      uint4 hh = *reinterpret_cast<const uint4*>(s_z2 + 32 + 4 * (rk + 16 * j));
      racc = dot2acc(wfc[4 * j + 0], hh.x, racc);
      racc = dot2acc(wfc[4 * j + 1], hh.y, racc);
      racc = dot2acc(wfc[4 * j + 2], hh.z, racc);
      racc = dot2acc(wfc[4 * j + 3], hh.w, racc);
    }
    racc += dpp_mov_f<DPP_XOR1>(racc);
    racc += dpp_mov_f<DPP_XOR2>(racc);
    racc += dpp_mov_f<DPP_HMIR>(racc);
    racc += dpp_mov_f<DPP_MIRR>(racc);
    if (rk == 0)
      out[out_row + (size_t)(T_ - 1) * O_ + ro] = racc + bfo;
  }

  if (tid < 128) {
    u32 hp = s_z2[32 + tid];
    float2 hv; hv.x = unpack_lo(hp); hv.y = unpack_hi(hp);
    ((float2*)(out + (size_t)B_ * T_ * O_))[r * 128 + tid] = hv;
  }
}

// Deferred readout: out[r,t,:] = H[r,t,:] @ W_fc + b_fc.
// Grid (B, 8): blockIdx.y picks a 128-step T-slice (16 chunks of 8 rows).
__global__ __launch_bounds__(512)
void ro_kernel(const u32* __restrict__ Hbuf,
               const float* __restrict__ W_fc, const float* __restrict__ b_fc,
               float* __restrict__ out)
{
  __shared__ __align__(16) u32 s_h[8 * 128];
  const int tid = threadIdx.x;
  const int o   = tid & 63;
  const int w   = tid >> 6;
  const int r   = blockIdx.x;
  const int c0  = blockIdx.y * 16;

  u32 wfc[128];
#pragma unroll
  for (int p = 0; p < 128; ++p)
    wfc[p] = packpair(W_fc[(2 * p) * O_ + o], W_fc[(2 * p + 1) * O_ + o]);
  const float bo = b_fc[o];

  const u32* hrow = Hbuf + (size_t)r * T_ * 128;
  const size_t out_row = (size_t)r * T_ * O_;

  for (int c = c0; c < c0 + 16; ++c) {
    *(uint2*)(s_h + 2 * tid) =
        *(const uint2*)(hrow + (size_t)c * 1024 + 2 * tid);
    __syncthreads();
    float acc = bo;
    const uint4* h4 = reinterpret_cast<const uint4*>(s_h + w * 128);
#pragma unroll
    for (int i = 0; i < 32; ++i) {
      uint4 hh = h4[i];
      acc = dot2acc(wfc[4 * i + 0], hh.x, acc);
      acc = dot2acc(wfc[4 * i + 1], hh.y, acc);
      acc = dot2acc(wfc[4 * i + 2], hh.z, acc);
      acc = dot2acc(wfc[4 * i + 3], hh.w, acc);
    }
    out[out_row + (size_t)(8 * c + w) * O_ + o] = acc;
    __syncthreads();
  }
}

extern "C" void kernel_launch(void* const* d_in, const int* in_sizes, int n_in,
                              void* d_out, int out_size, void* d_ws, size_t ws_size,
                              hipStream_t stream) {
  const float* x     = (const float*)d_in[0];
  const float* W_bb  = (const float*)d_in[1];
  const float* b_bb  = (const float*)d_in[2];
  const float* W_ff1 = (const float*)d_in[3];
  const float* b_ff1 = (const float*)d_in[4];
  const float* W_ff2 = (const float*)d_in[5];
  const float* b_ff2 = (const float*)d_in[6];
  const float* W_ta  = (const float*)d_in[7];
  const float* b_ta  = (const float*)d_in[8];
  const float* W_tb  = (const float*)d_in[9];
  const float* b_tb  = (const float*)d_in[10];
  const float* W_fc  = (const float*)d_in[11];
  const float* b_fc  = (const float*)d_in[12];
  float* out = (float*)d_out;

  const size_t h_bytes = (size_t)B_ * T_ * (U_ / 2) * sizeof(u32);  // 128 MiB
  if (ws_size >= h_bytes) {
    u32* Hbuf = (u32*)d_ws;
    cfc_mfma<<<dim3(B_ / 16), dim3(1024), 0, stream>>>(
        x, W_bb, b_bb, W_ff1, b_ff1, W_ff2, b_ff2,
        W_ta, b_ta, W_tb, b_tb, out, Hbuf);
    ro_kernel<<<dim3(B_, 8), dim3(512), 0, stream>>>(Hbuf, W_fc, b_fc, out);
  } else {
    cfc_kernel<false><<<dim3(B_), dim3(1024), 0, stream>>>(
        x, W_bb, b_bb, W_ff1, b_ff1, W_ff2, b_ff2,
        W_ta, b_ta, W_tb, b_tb, W_fc, b_fc, out, nullptr);
  }
}

// Round 5
// 1850.798 us; speedup vs baseline: 1.0853x; 1.0853x over previous
//
#include <hip/hip_runtime.h>
#include <stdint.h>

// CfC RNN: B=256, T=1024, I=64, U=256, O=64, BB=128. All I/O float32.
//
// Round 5: back to the r1 skeleton (8 waves, __syncthreads, linear LDS --
// empirically fastest at 1564 us; r3/r4 scheduling variants regressed), with
// the step itself shrunk:
//  - px_kernel precomputes Px[b,t] = x[b,t]@W_bb[0:64,:] + b_bb for ALL t in
//    parallel (whole chip), stored f16-packed in the main kernel's D-frag
//    layout. In-loop: one coalesced uint2 load -> MFMA acc init. Removes
//    2 bb MFMAs, 2 ds_reads, x prefetch/staging, bias add from every step.
//  - one-rcp h epilogue (r4-validated): 4 trans/h instead of 6.
// Workspace: Hbuf 128 MiB + Px 64 MiB. If ws < 192 MiB -> PX=false twin
// (r1 + new epilogue). If ws < 128 MiB -> dot2 fallback.
#define B_ 256
#define T_ 1024
#define I_ 64
#define U_ 256
#define O_ 64
#define BB_ 128

typedef unsigned int u32;
typedef unsigned short u16;
typedef _Float16 half2_t __attribute__((ext_vector_type(2)));
typedef _Float16 f16x8 __attribute__((ext_vector_type(8)));
typedef float f32x4 __attribute__((ext_vector_type(4)));

#if defined(__has_builtin)
#if __has_builtin(__builtin_amdgcn_fdot2)
#define USE_DOT2 1
#else
#define USE_DOT2 0
#endif
#else
#define USE_DOT2 0
#endif

static __device__ __forceinline__ u32 packpair(float a, float b) {
  half2_t h; h.x = (_Float16)a; h.y = (_Float16)b;
  return __builtin_bit_cast(u32, h);
}
static __device__ __forceinline__ float unpack_lo(u32 u) {
  half2_t h = __builtin_bit_cast(half2_t, u); return (float)h.x;
}
static __device__ __forceinline__ float unpack_hi(u32 u) {
  half2_t h = __builtin_bit_cast(half2_t, u); return (float)h.y;
}
static __device__ __forceinline__ float dot2acc(u32 w, u32 z, float acc) {
#if USE_DOT2
  return __builtin_amdgcn_fdot2(__builtin_bit_cast(half2_t, w),
                                __builtin_bit_cast(half2_t, z), acc, false);
#else
  half2_t hw = __builtin_bit_cast(half2_t, w);
  half2_t hz = __builtin_bit_cast(half2_t, z);
  acc += (float)hw.x * (float)hz.x;
  acc += (float)hw.y * (float)hz.y;
  return acc;
#endif
}

// DPP cross-lane moves (VALU pipe; no LDS). Palindromic controls only.
template <int CTRL>
static __device__ __forceinline__ float dpp_mov_f(float v) {
  return __builtin_bit_cast(float, __builtin_amdgcn_update_dpp(
      0, __builtin_bit_cast(int, v), CTRL, 0xF, 0xF, true));
}
#define DPP_XOR1 0xB1
#define DPP_XOR2 0x4E
#define DPP_HMIR 0x141
#define DPP_MIRR 0x140

static __device__ __forceinline__ float fast_tanh(float x) {
  return 1.0f - 2.0f / (1.0f + __expf(2.0f * x));
}
static __device__ __forceinline__ float fast_sigmoid(float x) {
  return 1.0f / (1.0f + __expf(-x));
}

static __device__ __forceinline__ float rcpf(float x) {
#if defined(__has_builtin) && __has_builtin(__builtin_amdgcn_rcpf)
  return __builtin_amdgcn_rcpf(x);
#else
  return 1.0f / x;
#endif
}
static __device__ __forceinline__ float exp2fast(float x) {
#if defined(__has_builtin) && __has_builtin(__builtin_amdgcn_exp2f)
  return __builtin_amdgcn_exp2f(x);
#else
  return exp2f(x);
#endif
}

static __device__ __forceinline__ f32x4 mfma16(uint4 a, uint4 b, f32x4 c) {
  return __builtin_amdgcn_mfma_f32_16x16x32_f16(
      __builtin_bit_cast(f16x8, a), __builtin_bit_cast(f16x8, b), c, 0, 0, 0);
}

#define LOG2E 1.44269504f

// ====================== Px pre-GEMM (x-path hoist) ========================
// Px[rr, t, w, lane] = D-frag of (x[rr*16..+15, t, :] @ W_bb[0:64,:] + b_bb)
// for n-tile w. Packed f16 pairs: (acc0,acc1),(acc2,acc3) -> uint2.
__global__ __launch_bounds__(512, 2)
void px_kernel(const float* __restrict__ x,
               const float* __restrict__ W_bb, const float* __restrict__ b_bb,
               u32* __restrict__ Px)
{
  const int tid = threadIdx.x;
  const int l   = tid & 63;
  const int w   = tid >> 6;        // n-tile 0..7
  const int c16 = l & 15;
  const int q4  = l >> 4;
  const int rr  = blockIdx.x;      // row-group 0..15
  const int t0  = blockIdx.y * 64; // 64 steps per WG

  // weights: rows k = c*32 + q4*8 + 2q (+1), k < 64; col = w*16 + c16
  uint4 wpx[2];
  {
    const int colb = w * 16 + c16;
#pragma unroll
    for (int c = 0; c < 2; ++c) {
      u32 qv[4];
#pragma unroll
      for (int q = 0; q < 4; ++q) {
        const int k0 = c * 32 + q4 * 8 + 2 * q;
        qv[q] = packpair(W_bb[(size_t)k0 * BB_ + colb],
                         W_bb[(size_t)(k0 + 1) * BB_ + colb]);
      }
      wpx[c] = make_uint4(qv[0], qv[1], qv[2], qv[3]);
    }
  }
  const float bc = b_bb[w * 16 + c16];

  // A rows = batch rows rr*16 + c16; k-slice base q4*8
  const float* xr = x + ((size_t)(rr * 16 + c16)) * T_ * I_ + q4 * 8;
  uint2* __restrict__ pxo =
      (uint2*)Px + ((size_t)rr * T_ + t0) * 512 + w * 64 + l;

  for (int i = 0; i < 64; ++i) {
    const int t = t0 + i;
    const float* xt = xr + (size_t)t * I_;
    float4 v0 = *(const float4*)(xt);
    float4 v1 = *(const float4*)(xt + 4);
    float4 v2 = *(const float4*)(xt + 32);
    float4 v3 = *(const float4*)(xt + 36);
    uint4 a0 = make_uint4(packpair(v0.x, v0.y), packpair(v0.z, v0.w),
                          packpair(v1.x, v1.y), packpair(v1.z, v1.w));
    uint4 a1 = make_uint4(packpair(v2.x, v2.y), packpair(v2.z, v2.w),
                          packpair(v3.x, v3.y), packpair(v3.z, v3.w));
    f32x4 acc = {bc, bc, bc, bc};
    acc = mfma16(a0, wpx[0], acc);
    acc = mfma16(a1, wpx[1], acc);
    uint2 o;
    o.x = packpair(acc[0], acc[1]);
    o.y = packpair(acc[2], acc[3]);
    pxo[(size_t)i * 512] = o;
  }
}

// ============================ MFMA main kernel ============================
template <bool PX>
__global__ __launch_bounds__(512, 2)
void cfc_mfma(const float* __restrict__ x,
              const float* __restrict__ W_bb, const float* __restrict__ b_bb,
              const float* __restrict__ W_ff1, const float* __restrict__ b_ff1,
              const float* __restrict__ W_ff2, const float* __restrict__ b_ff2,
              const float* __restrict__ W_ta,  const float* __restrict__ b_ta,
              const float* __restrict__ W_tb,  const float* __restrict__ b_tb,
              float* __restrict__ out, u32* __restrict__ Hbuf,
              const u32* __restrict__ Px)
{
  // z A-frags: [10 chunks][64 lanes][4 u32]; chunks 0..1 = x (unused if PX),
  // chunks 2..9 = h (k=64..319).
  __shared__ __align__(16) u32 s_z[2560];
  // g A-frags: [4 chunks][64 lanes][4 u32]
  __shared__ __align__(16) u32 s_g[1024];

  const int tid = threadIdx.x;
  const int l   = tid & 63;
  const int w   = tid >> 6;        // wave 0..7
  const int c16 = l & 15;
  const int q4  = l >> 4;
  const int odd = l & 1;
  const int rr  = blockIdx.x;
  const int row0 = rr * 16;

  // ---- bb weights: PX -> 8 chunks (k=64..319); !PX -> 10 chunks (k=0..319)
  const int NBB = PX ? 8 : 10;
  const int KOFF = PX ? 64 : 0;
  uint4 wbb[10];
  {
    const int colb = w * 16 + c16;
    for (int c = 0; c < NBB; ++c) {
      u32 qv[4];
#pragma unroll
      for (int q = 0; q < 4; ++q) {
        const int k0 = KOFF + c * 32 + q4 * 8 + 2 * q;
        qv[q] = packpair(W_bb[(size_t)k0 * BB_ + colb],
                         W_bb[(size_t)(k0 + 1) * BB_ + colb]);
      }
      wbb[c] = make_uint4(qv[0], qv[1], qv[2], qv[3]);
    }
  }
  // ---- ff weights: wave w owns units w*32..w*32+31 (2 tiles) x 3 mats ----
  uint4 wff[3][2][4];
#pragma unroll
  for (int ut = 0; ut < 2; ++ut) {
    const int u = w * 32 + ut * 16 + c16;
#pragma unroll
    for (int c = 0; c < 4; ++c) {
      u32 qa[4], qb[4], qc[4];
#pragma unroll
      for (int q = 0; q < 4; ++q) {
        const int k0 = c * 32 + q4 * 8 + 2 * q;
        const size_t i0 = (size_t)k0 * U_ + u, i1 = i0 + U_;
        qa[q] = packpair(W_ff1[i0], W_ff1[i1]);
        qb[q] = packpair(W_ff2[i0], W_ff2[i1]);
        qc[q] = packpair(W_ta[i0] + W_tb[i0], W_ta[i1] + W_tb[i1]);
      }
      wff[0][ut][c] = make_uint4(qa[0], qa[1], qa[2], qa[3]);
      wff[1][ut][c] = make_uint4(qb[0], qb[1], qb[2], qb[3]);
      wff[2][ut][c] = make_uint4(qc[0], qc[1], qc[2], qc[3]);
    }
  }

  // ---- biases (pre-scaled). PX: b_bb already folded into Px -> bgs = 0.
  const float bgs = PX ? 0.f : b_bb[w * 16 + c16] * (1.332f * LOG2E);
  float b1s[2], b2s[2], btn[2];
#pragma unroll
  for (int ut = 0; ut < 2; ++ut) {
    const int u = w * 32 + ut * 16 + c16;
    b1s[ut] = b_ff1[u] * (2.0f * LOG2E);
    b2s[ut] = b_ff2[u] * (2.0f * LOG2E);
    btn[ut] = -(b_ta[u] + b_tb[u]) * LOG2E;
  }

  // ---- x staging map (only used when !PX) ----
  const int mx = tid >> 5, px_ = tid & 31;
  const float* xptr = x + (size_t)(row0 + mx) * T_ * I_ + 2 * px_;
  const int zxw = ((px_ >> 4) * 64 + mx + 16 * ((px_ >> 2) & 3)) * 4 + (px_ & 3);

  // ---- Px stream (only used when PX) ----
  const uint2* pxp = (const uint2*)Px + (size_t)rr * T_ * 512 + w * 64 + l;

  // ---- g/h staging write addresses (D-frag -> A-frag repack), r1 layout --
  const int rbase = odd ? 2 : 0;
  const int m0 = q4 * 4 + rbase, m1 = m0 + 1;
  const int pg = w * 8 + (c16 >> 1);
  const int gw0 = ((pg >> 4) * 64 + 16 * ((pg >> 2) & 3)) * 4 + (pg & 3)
                  + 16 * q4 + (odd ? 8 : 0);
  int zw_[2]; size_t hb0_[2], hb1_[2];
#pragma unroll
  for (int ut = 0; ut < 2; ++ut) {
    const int pu = w * 16 + ut * 8 + (c16 >> 1);
    zw_[ut] = ((2 + (pu >> 4)) * 64 + 16 * ((pu >> 2) & 3)) * 4 + (pu & 3)
              + 16 * q4 + (odd ? 8 : 0);
    hb0_[ut] = (size_t)(row0 + m0) * T_ * 128 + pu;
    hb1_[ut] = (size_t)(row0 + m1) * T_ * 128 + pu;
  }

  // ---- prologue: h = 0 (chunks 2..9); stage x_0 / load Px_0 ----
  reinterpret_cast<uint4*>(s_z)[128 + tid] = make_uint4(0u, 0u, 0u, 0u);
  uint2 pxc;
  if (PX) {
    pxc = pxp[0];
  } else {
    __syncthreads();
    float2 xv = *(const float2*)xptr;
    s_z[zxw] = packpair(xv.x, xv.y);
  }
  __syncthreads();

  const uint4* z4 = (const uint4*)s_z;
  const uint4* g4 = (const uint4*)s_g;

  for (int t = 0; t < T_; ++t) {
    // prefetch next step's independent input (Px or x)
    uint2 pxn;
    float2 xv;
    const bool more = (t + 1 < T_);
    if (PX) {
      if (more) pxn = pxp[(size_t)(t + 1) * 512];
    } else {
      if (more) xv = *(const float2*)(xptr + (size_t)(t + 1) * I_);
    }

    // ================= backbone: G = Z @ W_bb (+ Px) =================
    f32x4 aA, aB = {0.f, 0.f, 0.f, 0.f};
    if (PX) {
      aA = (f32x4){unpack_lo(pxc.x), unpack_hi(pxc.x),
                   unpack_lo(pxc.y), unpack_hi(pxc.y)};
      aA = mfma16(z4[2 * 64 + l], wbb[0], aA);
      aB = mfma16(z4[3 * 64 + l], wbb[1], aB);
      aA = mfma16(z4[4 * 64 + l], wbb[2], aA);
      aB = mfma16(z4[5 * 64 + l], wbb[3], aB);
      aA = mfma16(z4[6 * 64 + l], wbb[4], aA);
      aB = mfma16(z4[7 * 64 + l], wbb[5], aB);
      aA = mfma16(z4[8 * 64 + l], wbb[6], aA);
      aB = mfma16(z4[9 * 64 + l], wbb[7], aB);
    } else {
      aA = (f32x4){0.f, 0.f, 0.f, 0.f};
#pragma unroll
      for (int c = 0; c < 10; c += 2) {
        aA = mfma16(z4[c * 64 + l],       wbb[c],     aA);
        aB = mfma16(z4[(c + 1) * 64 + l], wbb[c + 1], aB);
      }
    }
    const f32x4 ab = aA + aB;

    // g = lecun_tanh(S); pack col-pairs; stage as ff A-frags
    u32 gq[4];
#pragma unroll
    for (int r = 0; r < 4; ++r) {
      const float a  = __builtin_fmaf(ab[r], 1.332f * LOG2E, bgs);
      const float rv = rcpf(exp2fast(a) + 1.0f);
      const float g  = __builtin_fmaf(rv, -3.4318f, 1.7159f);
      const float gp = dpp_mov_f<DPP_XOR1>(g);
      gq[r] = odd ? packpair(gp, g) : packpair(g, gp);
    }
    s_g[gw0]     = odd ? gq[2] : gq[0];
    s_g[gw0 + 4] = odd ? gq[3] : gq[1];
    __syncthreads();

    // ================= ff: [E1|E2|E3] = G @ Wcat =================
    f32x4 af[3][2];
#pragma unroll
    for (int mt = 0; mt < 3; ++mt)
#pragma unroll
      for (int ut = 0; ut < 2; ++ut)
        af[mt][ut] = (f32x4){0.f, 0.f, 0.f, 0.f};
#pragma unroll
    for (int c = 0; c < 4; ++c) {
      const uint4 ga = g4[c * 64 + l];
#pragma unroll
      for (int mt = 0; mt < 3; ++mt)
#pragma unroll
        for (int ut = 0; ut < 2; ++ut)
          af[mt][ut] = mfma16(ga, wff[mt][ut][c], af[mt][ut]);
    }

    // ============ combine -> h (one-rcp form); stage; Hbuf ============
#pragma unroll
    for (int ut = 0; ut < 2; ++ut) {
      u32 hq[4];
#pragma unroll
      for (int r = 0; r < 4; ++r) {
        const float E1 = exp2fast(__builtin_fmaf(af[0][ut][r], 2.0f * LOG2E, b1s[ut]));
        const float E2 = exp2fast(__builtin_fmaf(af[1][ut][r], 2.0f * LOG2E, b2s[ut]));
        const float E3 = exp2fast(__builtin_fmaf(af[2][ut][r], -LOG2E, btn[ut]));
        const float p2 = E2 + 1.0f, p3 = E3 + 1.0f;
        const float qq = p2 * p3;
        const float D  = __builtin_fmaf(E1, qq, qq);   // (E1+1)(E2+1)(E3+1)
        const float R  = rcpf(D);
        const float u2 = (E2 - E1) - qq;
        const float h  = __builtin_fmaf(R + R, u2, 1.0f);
        const float hp = dpp_mov_f<DPP_XOR1>(h);
        hq[r] = odd ? packpair(hp, h) : packpair(h, hp);
      }
      const u32 s0 = odd ? hq[2] : hq[0];
      const u32 s1 = odd ? hq[3] : hq[1];
      s_z[zw_[ut]]     = s0;
      s_z[zw_[ut] + 4] = s1;
      Hbuf[hb0_[ut] + (size_t)t * 128] = s0;
      Hbuf[hb1_[ut] + (size_t)t * 128] = s1;
    }
    if (PX) {
      pxc = pxn;
    } else {
      if (more) s_z[zxw] = packpair(xv.x, xv.y);
    }
    __syncthreads();
  }

  // ---- h_last tail: unpack h region of s_z -> out + B*T*O as float2 ----
  {
    const uint4 hv = reinterpret_cast<const uint4*>(s_z)[128 + tid];
    float2* tail = (float2*)(out + (size_t)B_ * T_ * O_);
#pragma unroll
    for (int i = 0; i < 4; ++i) {
      const int vh   = tid * 4 + i;
      const int ch   = vh >> 8;
      const int lane = (vh >> 2) & 63;
      const int slot = vh & 3;
      const int m    = lane & 15;
      const int bq   = lane >> 4;
      const int pu   = ch * 16 + bq * 4 + slot;
      const u32 hp   = (i == 0) ? hv.x : (i == 1) ? hv.y : (i == 2) ? hv.z : hv.w;
      float2 hf; hf.x = unpack_lo(hp); hf.y = unpack_hi(hp);
      tail[(size_t)(row0 + m) * 128 + pu] = hf;
    }
  }
}

// ================= fallback (no workspace): dot2 kernel ==========
template <bool DEFER>
__global__ __launch_bounds__(1024)
void cfc_kernel(const float* __restrict__ x,
                const float* __restrict__ W_bb, const float* __restrict__ b_bb,
                const float* __restrict__ W_ff1, const float* __restrict__ b_ff1,
                const float* __restrict__ W_ff2, const float* __restrict__ b_ff2,
                const float* __restrict__ W_ta,  const float* __restrict__ b_ta,
                const float* __restrict__ W_tb,  const float* __restrict__ b_tb,
                const float* __restrict__ W_fc,  const float* __restrict__ b_fc,
                float* __restrict__ out, u32* __restrict__ Hbuf)
{
  __shared__ __align__(16) u32 s_z2[160];
  __shared__ __align__(16) u32 s_g2[64];
  u16* s_gh = (u16*)s_g2;

  const int tid = threadIdx.x;
  const int r   = blockIdx.x;

  const int ca  = tid >> 3;
  const int kga = tid & 7;
  const int jb = tid >> 2;
  const int kq = tid & 3;
  const int ro = tid >> 4;
  const int rk = tid & 15;

  u32 wbb[20];
#pragma unroll
  for (int j = 0; j < 5; ++j)
#pragma unroll
    for (int q = 0; q < 4; ++q) {
      int p = 4 * (kga + 8 * j) + q;
      wbb[4 * j + q] = packpair(W_bb[(2 * p) * BB_ + ca],
                                W_bb[(2 * p + 1) * BB_ + ca]);
    }
  u32 wf1[16], wf2[16], wta[16], wtb[16];
#pragma unroll
  for (int j = 0; j < 4; ++j)
#pragma unroll
    for (int q = 0; q < 4; ++q) {
      int p = 4 * (kq + 4 * j) + q;
      int k0 = 2 * p, k1 = 2 * p + 1;
      wf1[4 * j + q] = packpair(W_ff1[k0 * U_ + jb], W_ff1[k1 * U_ + jb]);
      wf2[4 * j + q] = packpair(W_ff2[k0 * U_ + jb], W_ff2[k1 * U_ + jb]);
      wta[4 * j + q] = packpair(W_ta [k0 * U_ + jb], W_ta [k1 * U_ + jb]);
      wtb[4 * j + q] = packpair(W_tb [k0 * U_ + jb], W_tb [k1 * U_ + jb]);
    }
  u32 wfc[8];
  float bfo = 0.f;
  if (!DEFER) {
#pragma unroll
    for (int j = 0; j < 2; ++j)
#pragma unroll
      for (int q = 0; q < 4; ++q) {
        int p = 4 * (rk + 16 * j) + q;
        wfc[4 * j + q] = packpair(W_fc[(2 * p) * O_ + ro],
                                  W_fc[(2 * p + 1) * O_ + ro]);
      }
    bfo = b_fc[ro];
  }
  const float bbbc = b_bb[ca];
  const float b1 = b_ff1[jb], b2 = b_ff2[jb];
  const float bta = b_ta[jb], btb = b_tb[jb];

  const float* xrow = x + (size_t)r * T_ * I_;
  const size_t out_row = (size_t)r * T_ * O_;
  u32* __restrict__ hrow = DEFER ? (Hbuf + (size_t)r * T_ * (U_ / 2)) : nullptr;

  if (tid < 160) s_z2[tid] = 0u;
  __syncthreads();
  if (tid < 32) {
    float2 xv = ((const float2*)xrow)[tid];
    s_z2[tid] = packpair(xv.x, xv.y);
  }
  __syncthreads();

  for (int t = 0; t < T_; ++t) {
    float2 xv;
    const bool ldx = (tid < 32) && (t + 1 < T_);
    if (ldx) xv = ((const float2*)(xrow + (size_t)(t + 1) * I_))[tid];

    float bacc = 0.f;
#pragma unroll
    for (int j = 0; j < 5; ++j) {
      uint4 zz = *reinterpret_cast<const uint4*>(s_z2 + 4 * (kga + 8 * j));
      bacc = dot2acc(wbb[4 * j + 0], zz.x, bacc);
      bacc = dot2acc(wbb[4 * j + 1], zz.y, bacc);
      bacc = dot2acc(wbb[4 * j + 2], zz.z, bacc);
      bacc = dot2acc(wbb[4 * j + 3], zz.w, bacc);
    }
    bacc += dpp_mov_f<DPP_XOR1>(bacc);
    bacc += dpp_mov_f<DPP_XOR2>(bacc);
    bacc += dpp_mov_f<DPP_HMIR>(bacc);
    float g = 1.7159f * fast_tanh(0.666f * (bacc + bbbc));

    float racc = 0.f;
    if (!DEFER) {
#pragma unroll
      for (int j = 0; j < 2; ++j) {
        uint4 hh = *reinterpret_cast<const uint4*>(s_z2 + 32 + 4 * (rk + 16 * j));
        racc = dot2acc(wfc[4 * j + 0], hh.x, racc);
        racc = dot2acc(wfc[4 * j + 1], hh.y, racc);
        racc = dot2acc(wfc[4 * j + 2], hh.z, racc);
        racc = dot2acc(wfc[4 * j + 3], hh.w, racc);
      }
      racc += dpp_mov_f<DPP_XOR1>(racc);
      racc += dpp_mov_f<DPP_XOR2>(racc);
      racc += dpp_mov_f<DPP_HMIR>(racc);
      racc += dpp_mov_f<DPP_MIRR>(racc);
    }
    if ((tid & 7) == 0)
      s_gh[ca] = __builtin_bit_cast(u16, (_Float16)g);
    if (!DEFER && t > 0 && rk == 0)
      out[out_row + (size_t)(t - 1) * O_ + ro] = racc + bfo;
    __syncthreads();

    float a1 = 0.f, a2 = 0.f, a3 = 0.f, a4 = 0.f;
#pragma unroll
    for (int j = 0; j < 4; ++j) {
      uint4 gg = *reinterpret_cast<const uint4*>(s_g2 + 4 * (kq + 4 * j));
      a1 = dot2acc(wf1[4 * j + 0], gg.x, a1);
      a1 = dot2acc(wf1[4 * j + 1], gg.y, a1);
      a1 = dot2acc(wf1[4 * j + 2], gg.z, a1);
      a1 = dot2acc(wf1[4 * j + 3], gg.w, a1);
      a2 = dot2acc(wf2[4 * j + 0], gg.x, a2);
      a2 = dot2acc(wf2[4 * j + 1], gg.y, a2);
      a2 = dot2acc(wf2[4 * j + 2], gg.z, a2);
      a2 = dot2acc(wf2[4 * j + 3], gg.w, a2);
      a3 = dot2acc(wta[4 * j + 0], gg.x, a3);
      a3 = dot2acc(wta[4 * j + 1], gg.y, a3);
      a3 = dot2acc(wta[4 * j + 2], gg.z, a3);
      a3 = dot2acc(wta[4 * j + 3], gg.w, a3);
      a4 = dot2acc(wtb[4 * j + 0], gg.x, a4);
      a4 = dot2acc(wtb[4 * j + 1], gg.y, a4);
      a4 = dot2acc(wtb[4 * j + 2], gg.z, a4);
      a4 = dot2acc(wtb[4 * j + 3], gg.w, a4);
    }
    a1 += dpp_mov_f<DPP_XOR1>(a1); a1 += dpp_mov_f<DPP_XOR2>(a1);
    a2 += dpp_mov_f<DPP_XOR1>(a2); a2 += dpp_mov_f<DPP_XOR2>(a2);
    a3 += dpp_mov_f<DPP_XOR1>(a3); a3 += dpp_mov_f<DPP_XOR2>(a3);
    a4 += dpp_mov_f<DPP_XOR1>(a4); a4 += dpp_mov_f<DPP_XOR2>(a4);
    float f1 = fast_tanh(a1 + b1);
    float f2 = fast_tanh(a2 + b2);
    float ti = fast_sigmoid(a3 + bta + a4 + btb);
    float h  = f1 + ti * (f2 - f1);
    float hq = dpp_mov_f<DPP_HMIR>(h);

    if ((tid & 7) == 0) {
      u32 pr = packpair(h, hq);
      int m = tid >> 3;
      s_z2[32 + m] = pr;
      if (DEFER) hrow[(size_t)t * (U_ / 2) + m] = pr;
    }
    if (ldx) s_z2[tid] = packpair(xv.x, xv.y);
    __syncthreads();
  }

  if (!DEFER) {
    float racc = 0.f;
#pragma unroll
    for (int j = 0; j < 2; ++j) {
      uint4 hh = *reinterpret_cast<const uint4*>(s_z2 + 32 + 4 * (rk + 16 * j));
      racc = dot2acc(wfc[4 * j + 0], hh.x, racc);
      racc = dot2acc(wfc[4 * j + 1], hh.y, racc);
      racc = dot2acc(wfc[4 * j + 2], hh.z, racc);
      racc = dot2acc(wfc[4 * j + 3], hh.w, racc);
    }
    racc += dpp_mov_f<DPP_XOR1>(racc);
    racc += dpp_mov_f<DPP_XOR2>(racc);
    racc += dpp_mov_f<DPP_HMIR>(racc);
    racc += dpp_mov_f<DPP_MIRR>(racc);
    if (rk == 0)
      out[out_row + (size_t)(T_ - 1) * O_ + ro] = racc + bfo;
  }

  if (tid < 128) {
    u32 hp = s_z2[32 + tid];
    float2 hv; hv.x = unpack_lo(hp); hv.y = unpack_hi(hp);
    ((float2*)(out + (size_t)B_ * T_ * O_))[r * 128 + tid] = hv;
  }
}

// Deferred readout: out[r,t,:] = H[r,t,:] @ W_fc + b_fc. (r1-proven form)
__global__ __launch_bounds__(512)
void ro_kernel(const u32* __restrict__ Hbuf,
               const float* __restrict__ W_fc, const float* __restrict__ b_fc,
               float* __restrict__ out)
{
  __shared__ __align__(16) u32 s_h[8 * 128];
  const int tid = threadIdx.x;
  const int o   = tid & 63;
  const int w   = tid >> 6;
  const int r   = blockIdx.x;

  u32 wfc[128];
#pragma unroll
  for (int p = 0; p < 128; ++p)
    wfc[p] = packpair(W_fc[(2 * p) * O_ + o], W_fc[(2 * p + 1) * O_ + o]);
  const float bo = b_fc[o];

  const u32* hrow = Hbuf + (size_t)r * T_ * 128;
  const size_t out_row = (size_t)r * T_ * O_;

  for (int c = 0; c < T_ / 8; ++c) {
    *(uint2*)(s_h + 2 * tid) =
        *(const uint2*)(hrow + (size_t)c * 1024 + 2 * tid);
    __syncthreads();
    float acc = bo;
    const uint4* h4 = reinterpret_cast<const uint4*>(s_h + w * 128);
#pragma unroll
    for (int i = 0; i < 32; ++i) {
      uint4 hh = h4[i];
      acc = dot2acc(wfc[4 * i + 0], hh.x, acc);
      acc = dot2acc(wfc[4 * i + 1], hh.y, acc);
      acc = dot2acc(wfc[4 * i + 2], hh.z, acc);
      acc = dot2acc(wfc[4 * i + 3], hh.w, acc);
    }
    out[out_row + (size_t)(8 * c + w) * O_ + o] = acc;
    __syncthreads();
  }
}

extern "C" void kernel_launch(void* const* d_in, const int* in_sizes, int n_in,
                              void* d_out, int out_size, void* d_ws, size_t ws_size,
                              hipStream_t stream) {
  const float* x     = (const float*)d_in[0];
  const float* W_bb  = (const float*)d_in[1];
  const float* b_bb  = (const float*)d_in[2];
  const float* W_ff1 = (const float*)d_in[3];
  const float* b_ff1 = (const float*)d_in[4];
  const float* W_ff2 = (const float*)d_in[5];
  const float* b_ff2 = (const float*)d_in[6];
  const float* W_ta  = (const float*)d_in[7];
  const float* b_ta  = (const float*)d_in[8];
  const float* W_tb  = (const float*)d_in[9];
  const float* b_tb  = (const float*)d_in[10];
  const float* W_fc  = (const float*)d_in[11];
  const float* b_fc  = (const float*)d_in[12];
  float* out = (float*)d_out;

  const size_t h_bytes  = (size_t)B_ * T_ * (U_ / 2) * sizeof(u32);  // 128 MiB
  const size_t px_bytes = (size_t)B_ * T_ * (BB_ / 2) * sizeof(u32); //  64 MiB
  if (ws_size >= h_bytes + px_bytes) {
    u32* Hbuf = (u32*)d_ws;
    u32* Px   = (u32*)((char*)d_ws + h_bytes);
    px_kernel<<<dim3(16, T_ / 64), dim3(512), 0, stream>>>(x, W_bb, b_bb, Px);
    cfc_mfma<true><<<dim3(B_ / 16), dim3(512), 0, stream>>>(
        x, W_bb, b_bb, W_ff1, b_ff1, W_ff2, b_ff2,
        W_ta, b_ta, W_tb, b_tb, out, Hbuf, Px);
    ro_kernel<<<dim3(B_), dim3(512), 0, stream>>>(Hbuf, W_fc, b_fc, out);
  } else if (ws_size >= h_bytes) {
    u32* Hbuf = (u32*)d_ws;
    cfc_mfma<false><<<dim3(B_ / 16), dim3(512), 0, stream>>>(
        x, W_bb, b_bb, W_ff1, b_ff1, W_ff2, b_ff2,
        W_ta, b_ta, W_tb, b_tb, out, Hbuf, nullptr);
    ro_kernel<<<dim3(B_), dim3(512), 0, stream>>>(Hbuf, W_fc, b_fc, out);
  } else {
    cfc_kernel<false><<<dim3(B_), dim3(1024), 0, stream>>>(
        x, W_bb, b_bb, W_ff1, b_ff1, W_ff2, b_ff2,
        W_ta, b_ta, W_tb, b_tb, W_fc, b_fc, out, nullptr);
  }
}

// Round 6
// 1649.393 us; speedup vs baseline: 1.2179x; 1.1221x over previous
//
#include <hip/hip_runtime.h>
#include <stdint.h>

// CfC RNN: B=256, T=1024, I=64, U=256, O=64, BB=128. All I/O float32.
//
// Round 6 (on r5's passing base, skeleton identical):
//  - h-path re-pairing: A/B fragment dwords in the h k-region now hold the
//    f16 pair (u, u+16) instead of (u, u+1). Both values of a pair are
//    computed by the SAME lane (ut=0/ut=1 tiles of one ff wave), so the
//    h-pack is a single v_cvt_pkrtz -- no DPP, no cndmask. W_bb gather,
//    LDS addresses, Hbuf layout, ro_kernel W_fc gather and the h_last tail
//    are re-derived for the new convention (self-consistent A/B k-map).
//    New scattered LDS h-writes get an XOR block swizzle -> conflict-free.
//  - delay-slot Hbuf stores: h(t-1) held in 4 regs, stored right after the
//    mid-step barrier of step t (drained at end barrier with ~1500cyc cover
//    instead of ~100).
//  - pkrtz packs in g-path and px_kernel.
// Tiers: ws>=192MiB: px+cfc_mfma2+ro<new>; >=128: r5 old kernel + ro<old>;
// else dot2 fallback.
#define B_ 256
#define T_ 1024
#define I_ 64
#define U_ 256
#define O_ 64
#define BB_ 128

typedef unsigned int u32;
typedef unsigned short u16;
typedef _Float16 half2_t __attribute__((ext_vector_type(2)));
typedef _Float16 f16x8 __attribute__((ext_vector_type(8)));
typedef float f32x4 __attribute__((ext_vector_type(4)));

#if defined(__has_builtin)
#if __has_builtin(__builtin_amdgcn_fdot2)
#define USE_DOT2 1
#else
#define USE_DOT2 0
#endif
#else
#define USE_DOT2 0
#endif

static __device__ __forceinline__ u32 packpair(float a, float b) {
  half2_t h; h.x = (_Float16)a; h.y = (_Float16)b;
  return __builtin_bit_cast(u32, h);
}
#if defined(__has_builtin) && __has_builtin(__builtin_amdgcn_cvt_pkrtz)
static __device__ __forceinline__ u32 pkrtz(float a, float b) {
  return __builtin_bit_cast(u32, __builtin_amdgcn_cvt_pkrtz(a, b));
}
#else
static __device__ __forceinline__ u32 pkrtz(float a, float b) {
  return packpair(a, b);
}
#endif
static __device__ __forceinline__ float unpack_lo(u32 u) {
  half2_t h = __builtin_bit_cast(half2_t, u); return (float)h.x;
}
static __device__ __forceinline__ float unpack_hi(u32 u) {
  half2_t h = __builtin_bit_cast(half2_t, u); return (float)h.y;
}
static __device__ __forceinline__ float dot2acc(u32 w, u32 z, float acc) {
#if USE_DOT2
  return __builtin_amdgcn_fdot2(__builtin_bit_cast(half2_t, w),
                                __builtin_bit_cast(half2_t, z), acc, false);
#else
  half2_t hw = __builtin_bit_cast(half2_t, w);
  half2_t hz = __builtin_bit_cast(half2_t, z);
  acc += (float)hw.x * (float)hz.x;
  acc += (float)hw.y * (float)hz.y;
  return acc;
#endif
}

// DPP cross-lane moves (VALU pipe; no LDS). Palindromic controls only.
template <int CTRL>
static __device__ __forceinline__ float dpp_mov_f(float v) {
  return __builtin_bit_cast(float, __builtin_amdgcn_update_dpp(
      0, __builtin_bit_cast(int, v), CTRL, 0xF, 0xF, true));
}
#define DPP_XOR1 0xB1
#define DPP_XOR2 0x4E
#define DPP_HMIR 0x141
#define DPP_MIRR 0x140

static __device__ __forceinline__ float fast_tanh(float x) {
  return 1.0f - 2.0f / (1.0f + __expf(2.0f * x));
}
static __device__ __forceinline__ float fast_sigmoid(float x) {
  return 1.0f / (1.0f + __expf(-x));
}

static __device__ __forceinline__ float rcpf(float x) {
#if defined(__has_builtin) && __has_builtin(__builtin_amdgcn_rcpf)
  return __builtin_amdgcn_rcpf(x);
#else
  return 1.0f / x;
#endif
}
static __device__ __forceinline__ float exp2fast(float x) {
#if defined(__has_builtin) && __has_builtin(__builtin_amdgcn_exp2f)
  return __builtin_amdgcn_exp2f(x);
#else
  return exp2f(x);
#endif
}

static __device__ __forceinline__ f32x4 mfma16(uint4 a, uint4 b, f32x4 c) {
  return __builtin_amdgcn_mfma_f32_16x16x32_f16(
      __builtin_bit_cast(f16x8, a), __builtin_bit_cast(f16x8, b), c, 0, 0, 0);
}

#define LOG2E 1.44269504f

// ====================== Px pre-GEMM (x-path hoist) ========================
// Px[rr, t, w, lane] = D-frag of (x[rr*16..+15, t, :] @ W_bb[0:64,:] + b_bb)
// for n-tile w. Packed f16 pairs (acc0,acc1),(acc2,acc3) -> uint2.
__global__ __launch_bounds__(512, 2)
void px_kernel(const float* __restrict__ x,
               const float* __restrict__ W_bb, const float* __restrict__ b_bb,
               u32* __restrict__ Px)
{
  const int tid = threadIdx.x;
  const int l   = tid & 63;
  const int w   = tid >> 6;        // n-tile 0..7
  const int c16 = l & 15;
  const int q4  = l >> 4;
  const int rr  = blockIdx.x;      // row-group 0..15
  const int t0  = blockIdx.y * 64; // 64 steps per WG

  uint4 wpx[2];
  {
    const int colb = w * 16 + c16;
#pragma unroll
    for (int c = 0; c < 2; ++c) {
      u32 qv[4];
#pragma unroll
      for (int q = 0; q < 4; ++q) {
        const int k0 = c * 32 + q4 * 8 + 2 * q;
        qv[q] = packpair(W_bb[(size_t)k0 * BB_ + colb],
                         W_bb[(size_t)(k0 + 1) * BB_ + colb]);
      }
      wpx[c] = make_uint4(qv[0], qv[1], qv[2], qv[3]);
    }
  }
  const float bc = b_bb[w * 16 + c16];

  const float* xr = x + ((size_t)(rr * 16 + c16)) * T_ * I_ + q4 * 8;
  uint2* __restrict__ pxo =
      (uint2*)Px + ((size_t)rr * T_ + t0) * 512 + w * 64 + l;

  for (int i = 0; i < 64; ++i) {
    const int t = t0 + i;
    const float* xt = xr + (size_t)t * I_;
    float4 v0 = *(const float4*)(xt);
    float4 v1 = *(const float4*)(xt + 4);
    float4 v2 = *(const float4*)(xt + 32);
    float4 v3 = *(const float4*)(xt + 36);
    uint4 a0 = make_uint4(pkrtz(v0.x, v0.y), pkrtz(v0.z, v0.w),
                          pkrtz(v1.x, v1.y), pkrtz(v1.z, v1.w));
    uint4 a1 = make_uint4(pkrtz(v2.x, v2.y), pkrtz(v2.z, v2.w),
                          pkrtz(v3.x, v3.y), pkrtz(v3.z, v3.w));
    f32x4 acc = {bc, bc, bc, bc};
    acc = mfma16(a0, wpx[0], acc);
    acc = mfma16(a1, wpx[1], acc);
    uint2 o;
    o.x = pkrtz(acc[0], acc[1]);
    o.y = pkrtz(acc[2], acc[3]);
    pxo[(size_t)i * 512] = o;
  }
}

// ==================== MFMA main kernel, round-6 (PX-only) =================
__global__ __launch_bounds__(512, 2)
void cfc_mfma2(const float* __restrict__ W_bb,
               const float* __restrict__ W_ff1, const float* __restrict__ b_ff1,
               const float* __restrict__ W_ff2, const float* __restrict__ b_ff2,
               const float* __restrict__ W_ta,  const float* __restrict__ b_ta,
               const float* __restrict__ W_tb,  const float* __restrict__ b_tb,
               float* __restrict__ out, u32* __restrict__ Hbuf,
               const u32* __restrict__ Px)
{
  // z A-frags: blocks [10 chunks][64 lanes] of uint4. Chunks 0..1 unused (x
  // folded into Px); chunks 2..9 = h with the NEW (u, u+16) pair convention
  // and XOR block swizzle (block ^= (block>>4)&3 within each 64-block chunk).
  __shared__ __align__(16) u32 s_z[2560];
  // g A-frags: [4 chunks][64 lanes][4 u32], OLD convention (unchanged).
  __shared__ __align__(16) u32 s_g[1024];

  const int tid = threadIdx.x;
  const int l   = tid & 63;
  const int w   = tid >> 6;        // wave 0..7
  const int c16 = l & 15;
  const int q4  = l >> 4;
  const int odd = l & 1;
  const int rr  = blockIdx.x;
  const int row0 = rr * 16;
  // swizzled consumer block lane for h-region reads
  const int lx  = l ^ (l >> 4);

  // ---- bb weights: 8 h-chunks, NEW pairing: dword q of (c,q4) holds
  //      W_bb rows (64 + u_lo, 64 + u_lo + 16), u_lo = 32c + 4q4 + q ----
  uint4 wbb[8];
  {
    const int colb = w * 16 + c16;
#pragma unroll
    for (int c = 0; c < 8; ++c) {
      u32 qv[4];
#pragma unroll
      for (int q = 0; q < 4; ++q) {
        const int ulo = 32 * c + 4 * q4 + q;
        qv[q] = packpair(W_bb[(size_t)(64 + ulo) * BB_ + colb],
                         W_bb[(size_t)(80 + ulo) * BB_ + colb]);
      }
      wbb[c] = make_uint4(qv[0], qv[1], qv[2], qv[3]);
    }
  }
  // ---- ff weights: wave w owns units w*32..w*32+31 (2 tiles) x 3 mats ----
  uint4 wff[3][2][4];
#pragma unroll
  for (int ut = 0; ut < 2; ++ut) {
    const int u = w * 32 + ut * 16 + c16;
#pragma unroll
    for (int c = 0; c < 4; ++c) {
      u32 qa[4], qb[4], qc[4];
#pragma unroll
      for (int q = 0; q < 4; ++q) {
        const int k0 = c * 32 + q4 * 8 + 2 * q;
        const size_t i0 = (size_t)k0 * U_ + u, i1 = i0 + U_;
        qa[q] = packpair(W_ff1[i0], W_ff1[i1]);
        qb[q] = packpair(W_ff2[i0], W_ff2[i1]);
        qc[q] = packpair(W_ta[i0] + W_tb[i0], W_ta[i1] + W_tb[i1]);
      }
      wff[0][ut][c] = make_uint4(qa[0], qa[1], qa[2], qa[3]);
      wff[1][ut][c] = make_uint4(qb[0], qb[1], qb[2], qb[3]);
      wff[2][ut][c] = make_uint4(qc[0], qc[1], qc[2], qc[3]);
    }
  }

  // ---- biases (pre-scaled; b_bb folded into Px) ----
  float b1s[2], b2s[2], btn[2];
#pragma unroll
  for (int ut = 0; ut < 2; ++ut) {
    const int u = w * 32 + ut * 16 + c16;
    b1s[ut] = b_ff1[u] * (2.0f * LOG2E);
    b2s[ut] = b_ff2[u] * (2.0f * LOG2E);
    btn[ut] = -(b_ta[u] + b_tb[u]) * LOG2E;
  }

  // ---- Px stream ----
  const uint2* pxp = (const uint2*)Px + (size_t)rr * T_ * 512 + w * 64 + l;

  // ---- g staging write addresses (OLD layout, unchanged from r5) ----
  const int pg = w * 8 + (c16 >> 1);
  const int gw0 = ((pg >> 4) * 64 + 16 * ((pg >> 2) & 3)) * 4 + (pg & 3)
                  + 16 * q4 + (odd ? 8 : 0);

  // ---- h staging write addresses, NEW convention ----
  // value pair for (row m = 4*q4 + r, u_lo = w*32 + c16):
  //   consumer chunk c = w, q4_cons = c16>>2, q = c16&3,
  //   lane_cons = m + 16*(c16>>2); logical block LB = (2+w)*64 + lane_cons;
  //   swizzled SB = LB ^ (c16>>2); word = SB*4 + (c16&3).
  int zws_[4];
#pragma unroll
  for (int r = 0; r < 4; ++r) {
    const int lane_cons = 4 * q4 + r + 16 * (c16 >> 2);
    const int LB = (2 + w) * 64 + lane_cons;
    const int SB = LB ^ (c16 >> 2);
    zws_[r] = SB * 4 + (c16 & 3);
  }
  // ---- Hbuf pointers: pu = w*16 + c16  <->  units (32*(pu>>4)+(pu&15), +16)
  u32* hp_[4];
#pragma unroll
  for (int r = 0; r < 4; ++r)
    hp_[r] = Hbuf + (size_t)(row0 + 4 * q4 + r) * T_ * 128 + (w * 16 + c16);

  // ---- prologue: h = 0 (blocks 128..639); load Px_0 ----
  reinterpret_cast<uint4*>(s_z)[128 + tid] = make_uint4(0u, 0u, 0u, 0u);
  uint2 pxc = pxp[0];
  __syncthreads();

  const uint4* z4 = (const uint4*)s_z;
  const uint4* g4 = (const uint4*)s_g;

  u32 hold0 = 0, hold1 = 0, hold2 = 0, hold3 = 0;

  for (int t = 0; t < T_; ++t) {
    // prefetch next Px (drained at mid barrier with ~bb-phase cover)
    uint2 pxn;
    const bool more = (t + 1 < T_);
    if (more) pxn = pxp[(size_t)(t + 1) * 512];

    // ================= backbone: G = Px + H @ W_bb[64:,:] =================
    f32x4 aA = {unpack_lo(pxc.x), unpack_hi(pxc.x),
                unpack_lo(pxc.y), unpack_hi(pxc.y)};
    f32x4 aB = {0.f, 0.f, 0.f, 0.f};
    aA = mfma16(z4[2 * 64 + lx], wbb[0], aA);
    aB = mfma16(z4[3 * 64 + lx], wbb[1], aB);
    aA = mfma16(z4[4 * 64 + lx], wbb[2], aA);
    aB = mfma16(z4[5 * 64 + lx], wbb[3], aB);
    aA = mfma16(z4[6 * 64 + lx], wbb[4], aA);
    aB = mfma16(z4[7 * 64 + lx], wbb[5], aB);
    aA = mfma16(z4[8 * 64 + lx], wbb[6], aA);
    aB = mfma16(z4[9 * 64 + lx], wbb[7], aB);
    const f32x4 ab = aA + aB;

    // g = lecun_tanh(S); pack col-pairs (OLD g convention); stage
    u32 gq[4];
#pragma unroll
    for (int r = 0; r < 4; ++r) {
      const float a  = ab[r] * (1.332f * LOG2E);
      const float rv = rcpf(exp2fast(a) + 1.0f);
      const float g  = __builtin_fmaf(rv, -3.4318f, 1.7159f);
      const float gp = dpp_mov_f<DPP_XOR1>(g);
      gq[r] = odd ? pkrtz(gp, g) : pkrtz(g, gp);
    }
    s_g[gw0]     = odd ? gq[2] : gq[0];
    s_g[gw0 + 4] = odd ? gq[3] : gq[1];
    __syncthreads();

    // delay-slot Hbuf stores for step t-1 (drained at END barrier, ~1500cyc
    // of ff+epilogue cover instead of ~100)
    if (t) {
      const size_t o = (size_t)(t - 1) * 128;
      hp_[0][o] = hold0; hp_[1][o] = hold1;
      hp_[2][o] = hold2; hp_[3][o] = hold3;
    }

    // ================= ff: [E1|E2|E3] = G @ Wcat =================
    f32x4 af[3][2];
#pragma unroll
    for (int mt = 0; mt < 3; ++mt)
#pragma unroll
      for (int ut = 0; ut < 2; ++ut)
        af[mt][ut] = (f32x4){0.f, 0.f, 0.f, 0.f};
#pragma unroll
    for (int c = 0; c < 4; ++c) {
      const uint4 ga = g4[c * 64 + l];
#pragma unroll
      for (int mt = 0; mt < 3; ++mt)
#pragma unroll
        for (int ut = 0; ut < 2; ++ut)
          af[mt][ut] = mfma16(ga, wff[mt][ut][c], af[mt][ut]);
    }

    // ===== combine -> h pairs (ut0,ut1) -> single pkrtz; stage; hold =====
    u32 pk0, pk1, pk2, pk3;
#pragma unroll
    for (int r = 0; r < 4; ++r) {
      float h01[2];
#pragma unroll
      for (int ut = 0; ut < 2; ++ut) {
        const float E1 = exp2fast(__builtin_fmaf(af[0][ut][r], 2.0f * LOG2E, b1s[ut]));
        const float E2 = exp2fast(__builtin_fmaf(af[1][ut][r], 2.0f * LOG2E, b2s[ut]));
        const float E3 = exp2fast(__builtin_fmaf(af[2][ut][r], -LOG2E, btn[ut]));
        const float p2 = E2 + 1.0f, p3 = E3 + 1.0f;
        const float qq = p2 * p3;
        const float D  = __builtin_fmaf(E1, qq, qq);   // (E1+1)(E2+1)(E3+1)
        const float R  = rcpf(D);
        const float u2 = (E2 - E1) - qq;
        h01[ut] = __builtin_fmaf(R + R, u2, 1.0f);
      }
      const u32 pkv = pkrtz(h01[0], h01[1]);
      s_z[zws_[r]] = pkv;
      if (r == 0) pk0 = pkv; else if (r == 1) pk1 = pkv;
      else if (r == 2) pk2 = pkv; else pk3 = pkv;
    }
    hold0 = pk0; hold1 = pk1; hold2 = pk2; hold3 = pk3;
    pxc = pxn;
    __syncthreads();
  }

  // final step's Hbuf stores
  {
    const size_t o = (size_t)(T_ - 1) * 128;
    hp_[0][o] = hold0; hp_[1][o] = hold1;
    hp_[2][o] = hold2; hp_[3][o] = hold3;
  }

  // ---- h_last tail: NEW convention readout -> out + B*T*O (f32 scalar) ----
  {
    const int c  = tid >> 6;          // h-chunk 0..7
    const int tl = tid & 63;          // consumer lane
    const uint4 hv = z4[(2 + c) * 64 + (tl ^ (tl >> 4))];
    const int row = row0 + (tl & 15);
    const int ub  = 32 * c + 4 * (tl >> 4);
    float* tail = out + (size_t)B_ * T_ * O_ + (size_t)row * 256;
#pragma unroll
    for (int q = 0; q < 4; ++q) {
      const u32 hp = (q == 0) ? hv.x : (q == 1) ? hv.y : (q == 2) ? hv.z : hv.w;
      tail[ub + q]      = unpack_lo(hp);
      tail[ub + q + 16] = unpack_hi(hp);
    }
  }
}

// ================= r5 kernel kept for the mid-ws tier (old pairing) =======
template <bool PX>
__global__ __launch_bounds__(512, 2)
void cfc_mfma(const float* __restrict__ x,
              const float* __restrict__ W_bb, const float* __restrict__ b_bb,
              const float* __restrict__ W_ff1, const float* __restrict__ b_ff1,
              const float* __restrict__ W_ff2, const float* __restrict__ b_ff2,
              const float* __restrict__ W_ta,  const float* __restrict__ b_ta,
              const float* __restrict__ W_tb,  const float* __restrict__ b_tb,
              float* __restrict__ out, u32* __restrict__ Hbuf,
              const u32* __restrict__ Px)
{
  __shared__ __align__(16) u32 s_z[2560];
  __shared__ __align__(16) u32 s_g[1024];

  const int tid = threadIdx.x;
  const int l   = tid & 63;
  const int w   = tid >> 6;
  const int c16 = l & 15;
  const int q4  = l >> 4;
  const int odd = l & 1;
  const int rr  = blockIdx.x;
  const int row0 = rr * 16;

  const int NBB = PX ? 8 : 10;
  const int KOFF = PX ? 64 : 0;
  uint4 wbb[10];
  {
    const int colb = w * 16 + c16;
    for (int c = 0; c < NBB; ++c) {
      u32 qv[4];
#pragma unroll
      for (int q = 0; q < 4; ++q) {
        const int k0 = KOFF + c * 32 + q4 * 8 + 2 * q;
        qv[q] = packpair(W_bb[(size_t)k0 * BB_ + colb],
                         W_bb[(size_t)(k0 + 1) * BB_ + colb]);
      }
      wbb[c] = make_uint4(qv[0], qv[1], qv[2], qv[3]);
    }
  }
  uint4 wff[3][2][4];
#pragma unroll
  for (int ut = 0; ut < 2; ++ut) {
    const int u = w * 32 + ut * 16 + c16;
#pragma unroll
    for (int c = 0; c < 4; ++c) {
      u32 qa[4], qb[4], qc[4];
#pragma unroll
      for (int q = 0; q < 4; ++q) {
        const int k0 = c * 32 + q4 * 8 + 2 * q;
        const size_t i0 = (size_t)k0 * U_ + u, i1 = i0 + U_;
        qa[q] = packpair(W_ff1[i0], W_ff1[i1]);
        qb[q] = packpair(W_ff2[i0], W_ff2[i1]);
        qc[q] = packpair(W_ta[i0] + W_tb[i0], W_ta[i1] + W_tb[i1]);
      }
      wff[0][ut][c] = make_uint4(qa[0], qa[1], qa[2], qa[3]);
      wff[1][ut][c] = make_uint4(qb[0], qb[1], qb[2], qb[3]);
      wff[2][ut][c] = make_uint4(qc[0], qc[1], qc[2], qc[3]);
    }
  }

  const float bgs = PX ? 0.f : b_bb[w * 16 + c16] * (1.332f * LOG2E);
  float b1s[2], b2s[2], btn[2];
#pragma unroll
  for (int ut = 0; ut < 2; ++ut) {
    const int u = w * 32 + ut * 16 + c16;
    b1s[ut] = b_ff1[u] * (2.0f * LOG2E);
    b2s[ut] = b_ff2[u] * (2.0f * LOG2E);
    btn[ut] = -(b_ta[u] + b_tb[u]) * LOG2E;
  }

  const int mx = tid >> 5, px_ = tid & 31;
  const float* xptr = x + (size_t)(row0 + mx) * T_ * I_ + 2 * px_;
  const int zxw = ((px_ >> 4) * 64 + mx + 16 * ((px_ >> 2) & 3)) * 4 + (px_ & 3);

  const uint2* pxp = (const uint2*)Px + (size_t)rr * T_ * 512 + w * 64 + l;

  const int rbase = odd ? 2 : 0;
  const int m0 = q4 * 4 + rbase, m1 = m0 + 1;
  const int pg = w * 8 + (c16 >> 1);
  const int gw0 = ((pg >> 4) * 64 + 16 * ((pg >> 2) & 3)) * 4 + (pg & 3)
                  + 16 * q4 + (odd ? 8 : 0);
  int zw_[2]; size_t hb0_[2], hb1_[2];
#pragma unroll
  for (int ut = 0; ut < 2; ++ut) {
    const int pu = w * 16 + ut * 8 + (c16 >> 1);
    zw_[ut] = ((2 + (pu >> 4)) * 64 + 16 * ((pu >> 2) & 3)) * 4 + (pu & 3)
              + 16 * q4 + (odd ? 8 : 0);
    hb0_[ut] = (size_t)(row0 + m0) * T_ * 128 + pu;
    hb1_[ut] = (size_t)(row0 + m1) * T_ * 128 + pu;
  }

  reinterpret_cast<uint4*>(s_z)[128 + tid] = make_uint4(0u, 0u, 0u, 0u);
  uint2 pxc;
  if (PX) {
    pxc = pxp[0];
  } else {
    __syncthreads();
    float2 xv = *(const float2*)xptr;
    s_z[zxw] = packpair(xv.x, xv.y);
  }
  __syncthreads();

  const uint4* z4 = (const uint4*)s_z;
  const uint4* g4 = (const uint4*)s_g;

  for (int t = 0; t < T_; ++t) {
    uint2 pxn;
    float2 xv;
    const bool more = (t + 1 < T_);
    if (PX) { if (more) pxn = pxp[(size_t)(t + 1) * 512]; }
    else    { if (more) xv = *(const float2*)(xptr + (size_t)(t + 1) * I_); }

    f32x4 aA, aB = {0.f, 0.f, 0.f, 0.f};
    if (PX) {
      aA = (f32x4){unpack_lo(pxc.x), unpack_hi(pxc.x),
                   unpack_lo(pxc.y), unpack_hi(pxc.y)};
      aA = mfma16(z4[2 * 64 + l], wbb[0], aA);
      aB = mfma16(z4[3 * 64 + l], wbb[1], aB);
      aA = mfma16(z4[4 * 64 + l], wbb[2], aA);
      aB = mfma16(z4[5 * 64 + l], wbb[3], aB);
      aA = mfma16(z4[6 * 64 + l], wbb[4], aA);
      aB = mfma16(z4[7 * 64 + l], wbb[5], aB);
      aA = mfma16(z4[8 * 64 + l], wbb[6], aA);
      aB = mfma16(z4[9 * 64 + l], wbb[7], aB);
    } else {
      aA = (f32x4){0.f, 0.f, 0.f, 0.f};
#pragma unroll
      for (int c = 0; c < 10; c += 2) {
        aA = mfma16(z4[c * 64 + l],       wbb[c],     aA);
        aB = mfma16(z4[(c + 1) * 64 + l], wbb[c + 1], aB);
      }
    }
    const f32x4 ab = aA + aB;

    u32 gq[4];
#pragma unroll
    for (int r = 0; r < 4; ++r) {
      const float a  = __builtin_fmaf(ab[r], 1.332f * LOG2E, bgs);
      const float rv = rcpf(exp2fast(a) + 1.0f);
      const float g  = __builtin_fmaf(rv, -3.4318f, 1.7159f);
      const float gp = dpp_mov_f<DPP_XOR1>(g);
      gq[r] = odd ? packpair(gp, g) : packpair(g, gp);
    }
    s_g[gw0]     = odd ? gq[2] : gq[0];
    s_g[gw0 + 4] = odd ? gq[3] : gq[1];
    __syncthreads();

    f32x4 af[3][2];
#pragma unroll
    for (int mt = 0; mt < 3; ++mt)
#pragma unroll
      for (int ut = 0; ut < 2; ++ut)
        af[mt][ut] = (f32x4){0.f, 0.f, 0.f, 0.f};
#pragma unroll
    for (int c = 0; c < 4; ++c) {
      const uint4 ga = g4[c * 64 + l];
#pragma unroll
      for (int mt = 0; mt < 3; ++mt)
#pragma unroll
        for (int ut = 0; ut < 2; ++ut)
          af[mt][ut] = mfma16(ga, wff[mt][ut][c], af[mt][ut]);
    }

#pragma unroll
    for (int ut = 0; ut < 2; ++ut) {
      u32 hq[4];
#pragma unroll
      for (int r = 0; r < 4; ++r) {
        const float E1 = exp2fast(__builtin_fmaf(af[0][ut][r], 2.0f * LOG2E, b1s[ut]));
        const float E2 = exp2fast(__builtin_fmaf(af[1][ut][r], 2.0f * LOG2E, b2s[ut]));
        const float E3 = exp2fast(__builtin_fmaf(af[2][ut][r], -LOG2E, btn[ut]));
        const float p2 = E2 + 1.0f, p3 = E3 + 1.0f;
        const float qq = p2 * p3;
        const float D  = __builtin_fmaf(E1, qq, qq);
        const float R  = rcpf(D);
        const float u2 = (E2 - E1) - qq;
        const float h  = __builtin_fmaf(R + R, u2, 1.0f);
        const float hp = dpp_mov_f<DPP_XOR1>(h);
        hq[r] = odd ? packpair(hp, h) : packpair(h, hp);
      }
      const u32 s0 = odd ? hq[2] : hq[0];
      const u32 s1 = odd ? hq[3] : hq[1];
      s_z[zw_[ut]]     = s0;
      s_z[zw_[ut] + 4] = s1;
      Hbuf[hb0_[ut] + (size_t)t * 128] = s0;
      Hbuf[hb1_[ut] + (size_t)t * 128] = s1;
    }
    if (PX) { pxc = pxn; }
    else    { if (more) s_z[zxw] = packpair(xv.x, xv.y); }
    __syncthreads();
  }

  {
    const uint4 hv = reinterpret_cast<const uint4*>(s_z)[128 + tid];
    float2* tail = (float2*)(out + (size_t)B_ * T_ * O_);
#pragma unroll
    for (int i = 0; i < 4; ++i) {
      const int vh   = tid * 4 + i;
      const int ch   = vh >> 8;
      const int lane = (vh >> 2) & 63;
      const int slot = vh & 3;
      const int m    = lane & 15;
      const int bq   = lane >> 4;
      const int pu   = ch * 16 + bq * 4 + slot;
      const u32 hp   = (i == 0) ? hv.x : (i == 1) ? hv.y : (i == 2) ? hv.z : hv.w;
      float2 hf; hf.x = unpack_lo(hp); hf.y = unpack_hi(hp);
      tail[(size_t)(row0 + m) * 128 + pu] = hf;
    }
  }
}

// ================= fallback (no workspace): dot2 kernel ==========
template <bool DEFER>
__global__ __launch_bounds__(1024)
void cfc_kernel(const float* __restrict__ x,
                const float* __restrict__ W_bb, const float* __restrict__ b_bb,
                const float* __restrict__ W_ff1, const float* __restrict__ b_ff1,
                const float* __restrict__ W_ff2, const float* __restrict__ b_ff2,
                const float* __restrict__ W_ta,  const float* __restrict__ b_ta,
                const float* __restrict__ W_tb,  const float* __restrict__ b_tb,
                const float* __restrict__ W_fc,  const float* __restrict__ b_fc,
                float* __restrict__ out, u32* __restrict__ Hbuf)
{
  __shared__ __align__(16) u32 s_z2[160];
  __shared__ __align__(16) u32 s_g2[64];
  u16* s_gh = (u16*)s_g2;

  const int tid = threadIdx.x;
  const int r   = blockIdx.x;

  const int ca  = tid >> 3;
  const int kga = tid & 7;
  const int jb = tid >> 2;
  const int kq = tid & 3;
  const int ro = tid >> 4;
  const int rk = tid & 15;

  u32 wbb[20];
#pragma unroll
  for (int j = 0; j < 5; ++j)
#pragma unroll
    for (int q = 0; q < 4; ++q) {
      int p = 4 * (kga + 8 * j) + q;
      wbb[4 * j + q] = packpair(W_bb[(2 * p) * BB_ + ca],
                                W_bb[(2 * p + 1) * BB_ + ca]);
    }
  u32 wf1[16], wf2[16], wta[16], wtb[16];
#pragma unroll
  for (int j = 0; j < 4; ++j)
#pragma unroll
    for (int q = 0; q < 4; ++q) {
      int p = 4 * (kq + 4 * j) + q;
      int k0 = 2 * p, k1 = 2 * p + 1;
      wf1[4 * j + q] = packpair(W_ff1[k0 * U_ + jb], W_ff1[k1 * U_ + jb]);
      wf2[4 * j + q] = packpair(W_ff2[k0 * U_ + jb], W_ff2[k1 * U_ + jb]);
      wta[4 * j + q] = packpair(W_ta [k0 * U_ + jb], W_ta [k1 * U_ + jb]);
      wtb[4 * j + q] = packpair(W_tb [k0 * U_ + jb], W_tb [k1 * U_ + jb]);
    }
  u32 wfc[8];
  float bfo = 0.f;
  if (!DEFER) {
#pragma unroll
    for (int j = 0; j < 2; ++j)
#pragma unroll
      for (int q = 0; q < 4; ++q) {
        int p = 4 * (rk + 16 * j) + q;
        wfc[4 * j + q] = packpair(W_fc[(2 * p) * O_ + ro],
                                  W_fc[(2 * p + 1) * O_ + ro]);
      }
    bfo = b_fc[ro];
  }
  const float bbbc = b_bb[ca];
  const float b1 = b_ff1[jb], b2 = b_ff2[jb];
  const float bta = b_ta[jb], btb = b_tb[jb];

  const float* xrow = x + (size_t)r * T_ * I_;
  const size_t out_row = (size_t)r * T_ * O_;
  u32* __restrict__ hrow = DEFER ? (Hbuf + (size_t)r * T_ * (U_ / 2)) : nullptr;

  if (tid < 160) s_z2[tid] = 0u;
  __syncthreads();
  if (tid < 32) {
    float2 xv = ((const float2*)xrow)[tid];
    s_z2[tid] = packpair(xv.x, xv.y);
  }
  __syncthreads();

  for (int t = 0; t < T_; ++t) {
    float2 xv;
    const bool ldx = (tid < 32) && (t + 1 < T_);
    if (ldx) xv = ((const float2*)(xrow + (size_t)(t + 1) * I_))[tid];

    float bacc = 0.f;
#pragma unroll
    for (int j = 0; j < 5; ++j) {
      uint4 zz = *reinterpret_cast<const uint4*>(s_z2 + 4 * (kga + 8 * j));
      bacc = dot2acc(wbb[4 * j + 0], zz.x, bacc);
      bacc = dot2acc(wbb[4 * j + 1], zz.y, bacc);
      bacc = dot2acc(wbb[4 * j + 2], zz.z, bacc);
      bacc = dot2acc(wbb[4 * j + 3], zz.w, bacc);
    }
    bacc += dpp_mov_f<DPP_XOR1>(bacc);
    bacc += dpp_mov_f<DPP_XOR2>(bacc);
    bacc += dpp_mov_f<DPP_HMIR>(bacc);
    float g = 1.7159f * fast_tanh(0.666f * (bacc + bbbc));

    float racc = 0.f;
    if (!DEFER) {
#pragma unroll
      for (int j = 0; j < 2; ++j) {
        uint4 hh = *reinterpret_cast<const uint4*>(s_z2 + 32 + 4 * (rk + 16 * j));
        racc = dot2acc(wfc[4 * j + 0], hh.x, racc);
        racc = dot2acc(wfc[4 * j + 1], hh.y, racc);
        racc = dot2acc(wfc[4 * j + 2], hh.z, racc);
        racc = dot2acc(wfc[4 * j + 3], hh.w, racc);
      }
      racc += dpp_mov_f<DPP_XOR1>(racc);
      racc += dpp_mov_f<DPP_XOR2>(racc);
      racc += dpp_mov_f<DPP_HMIR>(racc);
      racc += dpp_mov_f<DPP_MIRR>(racc);
    }
    if ((tid & 7) == 0)
      s_gh[ca] = __builtin_bit_cast(u16, (_Float16)g);
    if (!DEFER && t > 0 && rk == 0)
      out[out_row + (size_t)(t - 1) * O_ + ro] = racc + bfo;
    __syncthreads();

    float a1 = 0.f, a2 = 0.f, a3 = 0.f, a4 = 0.f;
#pragma unroll
    for (int j = 0; j < 4; ++j) {
      uint4 gg = *reinterpret_cast<const uint4*>(s_g2 + 4 * (kq + 4 * j));
      a1 = dot2acc(wf1[4 * j + 0], gg.x, a1);
      a1 = dot2acc(wf1[4 * j + 1], gg.y, a1);
      a1 = dot2acc(wf1[4 * j + 2], gg.z, a1);
      a1 = dot2acc(wf1[4 * j + 3], gg.w, a1);
      a2 = dot2acc(wf2[4 * j + 0], gg.x, a2);
      a2 = dot2acc(wf2[4 * j + 1], gg.y, a2);
      a2 = dot2acc(wf2[4 * j + 2], gg.z, a2);
      a2 = dot2acc(wf2[4 * j + 3], gg.w, a2);
      a3 = dot2acc(wta[4 * j + 0], gg.x, a3);
      a3 = dot2acc(wta[4 * j + 1], gg.y, a3);
      a3 = dot2acc(wta[4 * j + 2], gg.z, a3);
      a3 = dot2acc(wta[4 * j + 3], gg.w, a3);
      a4 = dot2acc(wtb[4 * j + 0], gg.x, a4);
      a4 = dot2acc(wtb[4 * j + 1], gg.y, a4);
      a4 = dot2acc(wtb[4 * j + 2], gg.z, a4);
      a4 = dot2acc(wtb[4 * j + 3], gg.w, a4);
    }
    a1 += dpp_mov_f<DPP_XOR1>(a1); a1 += dpp_mov_f<DPP_XOR2>(a1);
    a2 += dpp_mov_f<DPP_XOR1>(a2); a2 += dpp_mov_f<DPP_XOR2>(a2);
    a3 += dpp_mov_f<DPP_XOR1>(a3); a3 += dpp_mov_f<DPP_XOR2>(a3);
    a4 += dpp_mov_f<DPP_XOR1>(a4); a4 += dpp_mov_f<DPP_XOR2>(a4);
    float f1 = fast_tanh(a1 + b1);
    float f2 = fast_tanh(a2 + b2);
    float ti = fast_sigmoid(a3 + bta + a4 + btb);
    float h  = f1 + ti * (f2 - f1);
    float hq = dpp_mov_f<DPP_HMIR>(h);

    if ((tid & 7) == 0) {
      u32 pr = packpair(h, hq);
      int m = tid >> 3;
      s_z2[32 + m] = pr;
      if (DEFER) hrow[(size_t)t * (U_ / 2) + m] = pr;
    }
    if (ldx) s_z2[tid] = packpair(xv.x, xv.y);
    __syncthreads();
  }

  if (!DEFER) {
    float racc = 0.f;
#pragma unroll
    for (int j = 0; j < 2; ++j) {
      uint4 hh = *reinterpret_cast<const uint4*>(s_z2 + 32 + 4 * (rk + 16 * j));
      racc = dot2acc(wfc[4 * j + 0], hh.x, racc);
      racc = dot2acc(wfc[4 * j + 1], hh.y, racc);
      racc = dot2acc(wfc[4 * j + 2], hh.z, racc);
      racc = dot2acc(wfc[4 * j + 3], hh.w, racc);
    }
    racc += dpp_mov_f<DPP_XOR1>(racc);
    racc += dpp_mov_f<DPP_XOR2>(racc);
    racc += dpp_mov_f<DPP_HMIR>(racc);
    racc += dpp_mov_f<DPP_MIRR>(racc);
    if (rk == 0)
      out[out_row + (size_t)(T_ - 1) * O_ + ro] = racc + bfo;
  }

  if (tid < 128) {
    u32 hp = s_z2[32 + tid];
    float2 hv; hv.x = unpack_lo(hp); hv.y = unpack_hi(hp);
    ((float2*)(out + (size_t)B_ * T_ * O_))[r * 128 + tid] = hv;
  }
}

// Deferred readout: out[r,t,:] = H[r,t,:] @ W_fc + b_fc.
// NEWPAIR: Hbuf dword pu holds units (32*(pu>>4)+(pu&15), +16).
// old:     Hbuf dword pu holds units (2pu, 2pu+1).
template <bool NEWPAIR>
__global__ __launch_bounds__(512)
void ro_kernel(const u32* __restrict__ Hbuf,
               const float* __restrict__ W_fc, const float* __restrict__ b_fc,
               float* __restrict__ out)
{
  __shared__ __align__(16) u32 s_h[8 * 128];
  const int tid = threadIdx.x;
  const int o   = tid & 63;
  const int w   = tid >> 6;
  const int r   = blockIdx.x;

  u32 wfc[128];
#pragma unroll
  for (int p = 0; p < 128; ++p) {
    if (NEWPAIR) {
      const int ulo = 32 * (p >> 4) + (p & 15);
      wfc[p] = packpair(W_fc[(size_t)ulo * O_ + o],
                        W_fc[(size_t)(ulo + 16) * O_ + o]);
    } else {
      wfc[p] = packpair(W_fc[(2 * p) * O_ + o], W_fc[(2 * p + 1) * O_ + o]);
    }
  }
  const float bo = b_fc[o];

  const u32* hrow = Hbuf + (size_t)r * T_ * 128;
  const size_t out_row = (size_t)r * T_ * O_;

  for (int c = 0; c < T_ / 8; ++c) {
    *(uint2*)(s_h + 2 * tid) =
        *(const uint2*)(hrow + (size_t)c * 1024 + 2 * tid);
    __syncthreads();
    float acc = bo;
    const uint4* h4 = reinterpret_cast<const uint4*>(s_h + w * 128);
#pragma unroll
    for (int i = 0; i < 32; ++i) {
      uint4 hh = h4[i];
      acc = dot2acc(wfc[4 * i + 0], hh.x, acc);
      acc = dot2acc(wfc[4 * i + 1], hh.y, acc);
      acc = dot2acc(wfc[4 * i + 2], hh.z, acc);
      acc = dot2acc(wfc[4 * i + 3], hh.w, acc);
    }
    out[out_row + (size_t)(8 * c + w) * O_ + o] = acc;
    __syncthreads();
  }
}

extern "C" void kernel_launch(void* const* d_in, const int* in_sizes, int n_in,
                              void* d_out, int out_size, void* d_ws, size_t ws_size,
                              hipStream_t stream) {
  const float* x     = (const float*)d_in[0];
  const float* W_bb  = (const float*)d_in[1];
  const float* b_bb  = (const float*)d_in[2];
  const float* W_ff1 = (const float*)d_in[3];
  const float* b_ff1 = (const float*)d_in[4];
  const float* W_ff2 = (const float*)d_in[5];
  const float* b_ff2 = (const float*)d_in[6];
  const float* W_ta  = (const float*)d_in[7];
  const float* b_ta  = (const float*)d_in[8];
  const float* W_tb  = (const float*)d_in[9];
  const float* b_tb  = (const float*)d_in[10];
  const float* W_fc  = (const float*)d_in[11];
  const float* b_fc  = (const float*)d_in[12];
  float* out = (float*)d_out;

  const size_t h_bytes  = (size_t)B_ * T_ * (U_ / 2) * sizeof(u32);  // 128 MiB
  const size_t px_bytes = (size_t)B_ * T_ * (BB_ / 2) * sizeof(u32); //  64 MiB
  if (ws_size >= h_bytes + px_bytes) {
    u32* Hbuf = (u32*)d_ws;
    u32* Px   = (u32*)((char*)d_ws + h_bytes);
    px_kernel<<<dim3(16, T_ / 64), dim3(512), 0, stream>>>(x, W_bb, b_bb, Px);
    cfc_mfma2<<<dim3(B_ / 16), dim3(512), 0, stream>>>(
        W_bb, W_ff1, b_ff1, W_ff2, b_ff2,
        W_ta, b_ta, W_tb, b_tb, out, Hbuf, Px);
    ro_kernel<true><<<dim3(B_), dim3(512), 0, stream>>>(Hbuf, W_fc, b_fc, out);
  } else if (ws_size >= h_bytes) {
    u32* Hbuf = (u32*)d_ws;
    cfc_mfma<false><<<dim3(B_ / 16), dim3(512), 0, stream>>>(
        x, W_bb, b_bb, W_ff1, b_ff1, W_ff2, b_ff2,
        W_ta, b_ta, W_tb, b_tb, out, Hbuf, nullptr);
    ro_kernel<false><<<dim3(B_), dim3(512), 0, stream>>>(Hbuf, W_fc, b_fc, out);
  } else {
    cfc_kernel<false><<<dim3(B_), dim3(1024), 0, stream>>>(
        x, W_bb, b_bb, W_ff1, b_ff1, W_ff2, b_ff2,
        W_ta, b_ta, W_tb, b_tb, W_fc, b_fc, out, nullptr);
  }
}